// Round 1
// baseline (639.778 us; speedup 1.0000x reference)
//
#include <hip/hip_runtime.h>

#define FD 128  // feature dim (D == H == 128)

// ---------------- degree / CSR build ----------------

__global__ void k_init_deg(int* __restrict__ degi, int* __restrict__ dego, int n) {
  int i = blockIdx.x * blockDim.x + threadIdx.x;
  if (i < n) { degi[i] = 1; dego[i] = 1; }  // self-loop contributes 1 to each
}

__global__ void k_count(const int* __restrict__ src, const int* __restrict__ dst,
                        int* __restrict__ dego, int* __restrict__ degi, int e) {
  int t = blockIdx.x * blockDim.x + threadIdx.x;
  if (t < e) {
    atomicAdd(&dego[src[t]], 1);
    atomicAdd(&degi[dst[t]], 1);
  }
}

// block-level exclusive scan (256/block), block sums out
__global__ void k_scanA(const int* __restrict__ deg, int* __restrict__ rp,
                        int* __restrict__ bsum, int n) {
  __shared__ int sm[256];
  int t = threadIdx.x;
  int i = blockIdx.x * 256 + t;
  int v = (i < n) ? deg[i] : 0;
  sm[t] = v;
  __syncthreads();
  for (int off = 1; off < 256; off <<= 1) {
    int add = (t >= off) ? sm[t - off] : 0;
    __syncthreads();
    sm[t] += add;
    __syncthreads();
  }
  if (i < n) rp[i] = sm[t] - v;           // exclusive
  if (t == 255) bsum[blockIdx.x] = sm[t]; // block total
}

// scan the block sums in place (exclusive). nb <= 512.
__global__ void k_scanB(int* __restrict__ bsum, int nb) {
  __shared__ int sm[512];
  int t = threadIdx.x;
  int v = (t < nb) ? bsum[t] : 0;
  sm[t] = v;
  __syncthreads();
  for (int off = 1; off < 512; off <<= 1) {
    int add = (t >= off) ? sm[t - off] : 0;
    __syncthreads();
    sm[t] += add;
    __syncthreads();
  }
  if (t < nb) bsum[t] = sm[t] - v;
}

__global__ void k_finalize(int* __restrict__ rp, const int* __restrict__ bsum,
                           int* __restrict__ cursor,
                           const int* __restrict__ dego, const int* __restrict__ degi,
                           float* __restrict__ nout, float* __restrict__ nin,
                           int n, int total) {
  int i = blockIdx.x * blockDim.x + threadIdx.x;
  if (i < n) {
    int r = rp[i] + bsum[i >> 8];
    rp[i] = r;
    cursor[i] = r;
    nout[i] = rsqrtf((float)dego[i]);  // deg >= 1 always (self-loop)
    nin[i]  = rsqrtf((float)degi[i]);
  }
  if (i == 0) rp[n] = total;
}

__global__ void k_fill(const int* __restrict__ src, const int* __restrict__ dst,
                       int* __restrict__ cursor, int* __restrict__ col, int e, int n) {
  int t = blockIdx.x * blockDim.x + threadIdx.x;
  if (t < e + n) {
    int s, d;
    if (t < e) { s = src[t]; d = dst[t]; }
    else       { s = t - e;  d = t - e;  }
    int p = atomicAdd(&cursor[d], 1);
    col[p] = s;
  }
}

// ---------------- aggregation: one wave per dst row ----------------
// agg[r] = norm_in[r] * sum_{s in col[rp[r]..rp[r+1])} norm_out[s] * h[s]

__global__ __launch_bounds__(256) void k_aggregate(
    const float* __restrict__ h, const int* __restrict__ rp,
    const int* __restrict__ col,
    const float* __restrict__ nout, const float* __restrict__ nin,
    float* __restrict__ agg, int n) {
  int wid = (blockIdx.x * blockDim.x + threadIdx.x) >> 6;
  int lane = threadIdx.x & 63;
  if (wid >= n) return;
  int e0 = rp[wid], e1 = rp[wid + 1];
  const float2* hv = (const float2*)h;  // 64 float2 per row
  float2 a0 = {0.f, 0.f}, a1 = {0.f, 0.f}, a2 = {0.f, 0.f}, a3 = {0.f, 0.f};
  int e = e0;
  for (; e + 4 <= e1; e += 4) {
    int s0 = col[e], s1 = col[e + 1], s2 = col[e + 2], s3 = col[e + 3];
    float w0 = nout[s0], w1 = nout[s1], w2 = nout[s2], w3 = nout[s3];
    float2 v0 = hv[s0 * 64 + lane];
    float2 v1 = hv[s1 * 64 + lane];
    float2 v2 = hv[s2 * 64 + lane];
    float2 v3 = hv[s3 * 64 + lane];
    a0.x += v0.x * w0; a0.y += v0.y * w0;
    a1.x += v1.x * w1; a1.y += v1.y * w1;
    a2.x += v2.x * w2; a2.y += v2.y * w2;
    a3.x += v3.x * w3; a3.y += v3.y * w3;
  }
  for (; e < e1; ++e) {
    int s0 = col[e];
    float w0 = nout[s0];
    float2 v0 = hv[s0 * 64 + lane];
    a0.x += v0.x * w0; a0.y += v0.y * w0;
  }
  float wi = nin[wid];
  float2 r;
  r.x = (a0.x + a1.x + a2.x + a3.x) * wi;
  r.y = (a0.y + a1.y + a2.y + a3.y) * wi;
  ((float2*)agg)[wid * 64 + lane] = r;
}

// ---------------- fp32 GEMM: out[n,128] = a[n,128] @ w[128,128] + bias ----------------
// block: 256 threads, 64-row tile, full 128 cols. thread (tx=tid%16, ty=tid/16)
// computes rows ty*4..+3, cols {tx + 16j, j=0..7}. K staged in chunks of 32.

__global__ __launch_bounds__(256) void k_gemm(
    const float* __restrict__ a, const float* __restrict__ w,
    const float* __restrict__ bias, float* __restrict__ out, int n) {
  __shared__ float As[64][33];   // padded: conflict-free row reads
  __shared__ float Ws[32][128];
  int tid = threadIdx.x;
  int tx = tid & 15, ty = tid >> 4;
  int r0 = blockIdx.x * 64;

  float acc[4][8];
  #pragma unroll
  for (int i = 0; i < 4; ++i)
    #pragma unroll
    for (int j = 0; j < 8; ++j) acc[i][j] = 0.f;

  float bj[8];
  #pragma unroll
  for (int j = 0; j < 8; ++j) bj[j] = bias[tx + 16 * j];

  int ar = tid >> 2, aq = tid & 3;   // A staging: row ar, 8-float chunk aq
  int kr = tid >> 3, cg = tid & 7;   // W staging: k-row kr, 16-col group cg

  for (int kc = 0; kc < 4; ++kc) {
    // load globals to regs
    float4 av0, av1;
    int grow = r0 + ar;
    if (grow < n) {
      const float4* ap = (const float4*)(a + (size_t)grow * FD + kc * 32 + aq * 8);
      av0 = ap[0]; av1 = ap[1];
    } else {
      av0 = make_float4(0.f, 0.f, 0.f, 0.f);
      av1 = make_float4(0.f, 0.f, 0.f, 0.f);
    }
    const float4* wp = (const float4*)(w + (size_t)(kc * 32 + kr) * FD + cg * 16);
    float4 wv0 = wp[0], wv1 = wp[1], wv2 = wp[2], wv3 = wp[3];

    __syncthreads();  // previous chunk's reads complete before overwrite
    As[ar][aq * 8 + 0] = av0.x; As[ar][aq * 8 + 1] = av0.y;
    As[ar][aq * 8 + 2] = av0.z; As[ar][aq * 8 + 3] = av0.w;
    As[ar][aq * 8 + 4] = av1.x; As[ar][aq * 8 + 5] = av1.y;
    As[ar][aq * 8 + 6] = av1.z; As[ar][aq * 8 + 7] = av1.w;
    *(float4*)&Ws[kr][cg * 16 + 0]  = wv0;
    *(float4*)&Ws[kr][cg * 16 + 4]  = wv1;
    *(float4*)&Ws[kr][cg * 16 + 8]  = wv2;
    *(float4*)&Ws[kr][cg * 16 + 12] = wv3;
    __syncthreads();

    #pragma unroll
    for (int k = 0; k < 32; ++k) {
      float avr[4];
      #pragma unroll
      for (int i = 0; i < 4; ++i) avr[i] = As[ty * 4 + i][k];
      float wvr[8];
      #pragma unroll
      for (int j = 0; j < 8; ++j) wvr[j] = Ws[k][tx + 16 * j];
      #pragma unroll
      for (int i = 0; i < 4; ++i)
        #pragma unroll
        for (int j = 0; j < 8; ++j)
          acc[i][j] += avr[i] * wvr[j];
    }
  }

  #pragma unroll
  for (int i = 0; i < 4; ++i) {
    int row = r0 + ty * 4 + i;
    if (row < n) {
      #pragma unroll
      for (int j = 0; j < 8; ++j)
        out[(size_t)row * FD + tx + 16 * j] = acc[i][j] + bj[j];
    }
  }
}

// ---------------- launch ----------------

extern "C" void kernel_launch(void* const* d_in, const int* in_sizes, int n_in,
                              void* d_out, int out_size, void* d_ws, size_t ws_size,
                              hipStream_t stream) {
  const float* x  = (const float*)d_in[0];
  const int* src  = (const int*)d_in[1];
  const int* dst  = (const int*)d_in[2];
  const float* W1 = (const float*)d_in[3];
  const float* b1 = (const float*)d_in[4];
  const float* W2 = (const float*)d_in[5];
  const float* b2 = (const float*)d_in[6];
  float* out = (float*)d_out;

  int n = in_sizes[0] / FD;   // 100000
  int e = in_sizes[1];        // 1600000

  // workspace layout
  char* ws = (char*)d_ws;
  size_t off = 0;
  auto alloc = [&](size_t bytes) -> void* {
    void* p = ws + off;
    off += (bytes + 255) / 256 * 256;
    return p;
  };
  float* agg   = (float*)alloc((size_t)n * FD * sizeof(float)); // 51.2 MB
  int* dego    = (int*)alloc((size_t)n * 4);
  int* degi    = (int*)alloc((size_t)n * 4);
  float* nout  = (float*)alloc((size_t)n * 4);
  float* nin   = (float*)alloc((size_t)n * 4);
  int* rp      = (int*)alloc((size_t)(n + 1) * 4);
  int* cursor  = (int*)alloc((size_t)n * 4);
  int* colb    = (int*)alloc((size_t)(e + n) * 4);               // 6.8 MB
  int* bsum    = (int*)alloc(4096);

  int nb = (n + 255) / 256;  // 391 (<= 512 for scanB)

  k_init_deg<<<nb, 256, 0, stream>>>(degi, dego, n);
  k_count<<<(e + 255) / 256, 256, 0, stream>>>(src, dst, dego, degi, e);
  k_scanA<<<nb, 256, 0, stream>>>(degi, rp, bsum, n);
  k_scanB<<<1, 512, 0, stream>>>(bsum, nb);
  k_finalize<<<nb, 256, 0, stream>>>(rp, bsum, cursor, dego, degi, nout, nin, n, e + n);
  k_fill<<<(e + n + 255) / 256, 256, 0, stream>>>(src, dst, cursor, colb, e, n);

  // layer 1: agg = normalized aggregate of x; h1 = agg @ W1 + b1 -> stored in d_out
  k_aggregate<<<(n + 3) / 4, 256, 0, stream>>>(x, rp, colb, nout, nin, agg, n);
  k_gemm<<<(n + 63) / 64, 256, 0, stream>>>(agg, W1, b1, out, n);

  // layer 2: agg = normalized aggregate of h1 (in d_out); out = agg @ W2 + b2
  k_aggregate<<<(n + 3) / 4, 256, 0, stream>>>(out, rp, colb, nout, nin, agg, n);
  k_gemm<<<(n + 63) / 64, 256, 0, stream>>>(agg, W2, b2, out, n);
}

// Round 2
// 458.902 us; speedup vs baseline: 1.3942x; 1.3942x over previous
//
#include <hip/hip_runtime.h>

#define FD 128
#define SHIFT 8          // nodes per bucket
#define BNODES 256
#define CHUNK 2048       // edges per scatter block
#define ST 512           // scatter block threads

// ---------- pass 0: bucket histogram over dst (incl. self-loops) ----------
__global__ __launch_bounds__(512) void k_hist(const int* __restrict__ dst,
                                              int* __restrict__ bcnt,
                                              int e, int n, int nbuck) {
  __shared__ int sh[512];
  int tid = threadIdx.x;
  sh[tid] = 0;
  __syncthreads();
  int total = e + n;
  for (int t = blockIdx.x * blockDim.x + tid; t < total; t += gridDim.x * blockDim.x) {
    int d = (t < e) ? dst[t] : (t - e);
    atomicAdd(&sh[d >> SHIFT], 1);
  }
  __syncthreads();
  if (tid < nbuck && sh[tid]) atomicAdd(&bcnt[tid], sh[tid]);
}

// ---------- pass 1: scan buckets ----------
__global__ __launch_bounds__(512) void k_bscan(const int* __restrict__ bcnt,
                                               int* __restrict__ bbase,
                                               int* __restrict__ bcur,
                                               int nbuck, int total) {
  __shared__ int sh[512];
  int tid = threadIdx.x;
  int v = (tid < nbuck) ? bcnt[tid] : 0;
  sh[tid] = v;
  __syncthreads();
  for (int off = 1; off < 512; off <<= 1) {
    int add = (tid >= off) ? sh[tid - off] : 0;
    __syncthreads();
    sh[tid] += add;
    __syncthreads();
  }
  if (tid < nbuck) { int ex = sh[tid] - v; bbase[tid] = ex; bcur[tid] = ex; }
  if (tid == 0) bbase[nbuck] = total;
}

// ---------- pass 2: locality-aware scatter of (src,dst) pairs by bucket ----------
__global__ __launch_bounds__(ST) void k_scatter(
    const int* __restrict__ src, const int* __restrict__ dst,
    int* __restrict__ bcur, int* __restrict__ dego,
    uint2* __restrict__ pairs, int e, int n, int nbuck) {
  __shared__ int hist[512];
  __shared__ int incl[512];
  __shared__ int excl[512];
  __shared__ int gbase[512];
  __shared__ uint2 stg[CHUNK];
  int tid = threadIdx.x;
  int c0 = blockIdx.x * CHUNK;
  int total = e + n;
  hist[tid] = 0;
  __syncthreads();
  int s_[4], d_[4], b_[4];
  bool v_[4];
  #pragma unroll
  for (int i = 0; i < 4; ++i) {
    int t = c0 + i * ST + tid;
    v_[i] = (t < total);
    s_[i] = 0; d_[i] = 0; b_[i] = 0;
    if (v_[i]) {
      int s, d;
      if (t < e) { s = src[t]; d = dst[t]; atomicAdd(&dego[s], 1); }
      else       { s = t - e;  d = s; }
      s_[i] = s; d_[i] = d; b_[i] = d >> SHIFT;
      atomicAdd(&hist[b_[i]], 1);
    }
  }
  __syncthreads();
  int h = hist[tid];
  incl[tid] = h;
  __syncthreads();
  for (int off = 1; off < 512; off <<= 1) {
    int add = (tid >= off) ? incl[tid - off] : 0;
    __syncthreads();
    incl[tid] += add;
    __syncthreads();
  }
  excl[tid] = incl[tid] - h;
  if (tid < nbuck && h > 0) gbase[tid] = atomicAdd(&bcur[tid], h);
  __syncthreads();
  hist[tid] = excl[tid];       // becomes local rank cursor
  __syncthreads();
  #pragma unroll
  for (int i = 0; i < 4; ++i) {
    if (v_[i]) {
      int p = atomicAdd(&hist[b_[i]], 1);
      stg[p] = make_uint2((unsigned)s_[i], (unsigned)d_[i]);
    }
  }
  __syncthreads();
  int V = min(CHUNK, total - c0);
  for (int j = tid; j < V; j += ST) {
    uint2 pr = stg[j];
    int b = (int)(pr.y >> SHIFT);
    pairs[gbase[b] + (j - excl[b])] = pr;   // contiguous runs per bucket
  }
}

// ---------- pass 3: per-bucket CSR finalize (rp, norms, col) ----------
__global__ __launch_bounds__(256) void k_build(
    const uint2* __restrict__ pairs, const int* __restrict__ bbase,
    const int* __restrict__ dego,
    int* __restrict__ rp, int* __restrict__ col,
    float* __restrict__ nin, float* __restrict__ nout,
    int n, int nbuck, int total) {
  __shared__ int cnt[256];
  __shared__ int off_[256];
  __shared__ int cur[256];
  int tid = threadIdx.x;
  int b = blockIdx.x;
  int base = bbase[b], end = bbase[b + 1];
  int node0 = b << SHIFT;
  cnt[tid] = 0;
  __syncthreads();
  for (int t = base + tid; t < end; t += 256)
    atomicAdd(&cnt[(int)(pairs[t].y) & (BNODES - 1)], 1);
  __syncthreads();
  int c = cnt[tid];
  off_[tid] = c;
  __syncthreads();
  for (int off = 1; off < 256; off <<= 1) {
    int add = (tid >= off) ? off_[tid - off] : 0;
    __syncthreads();
    off_[tid] += add;
    __syncthreads();
  }
  int ex = off_[tid] - c;
  int node = node0 + tid;
  if (node < n) {
    rp[node] = base + ex;
    nin[node] = rsqrtf((float)c);              // includes self-loop
    nout[node] = rsqrtf((float)(dego[node] + 1));
  }
  if (b == nbuck - 1 && tid == 0) rp[n] = total;
  cur[tid] = ex;
  __syncthreads();
  for (int t = base + tid; t < end; t += 256) {
    uint2 pr = pairs[t];
    int p = atomicAdd(&cur[(int)pr.y & (BNODES - 1)], 1);
    col[base + p] = (int)pr.x;                 // writes stay in one L2-local region
  }
}

// ---------- fused layer: aggregate 32 rows to LDS, then GEMM + bias ----------
// out[r] = (nin[r] * sum_{s in N(r)} nout[s]*h[s]) @ W + bias
__global__ __launch_bounds__(256) void k_layer(
    const float* __restrict__ h, const int* __restrict__ rp,
    const int* __restrict__ col,
    const float* __restrict__ nout, const float* __restrict__ nin,
    const float* __restrict__ W, const float* __restrict__ bias,
    float* __restrict__ out, int n) {
  __shared__ float As[32][132];
  __shared__ float Ws[16][132];
  int tid = threadIdx.x;
  int lane = tid & 63;
  int wv = tid >> 6;
  int r0 = blockIdx.x * 32;
  const float2* hv = (const float2*)h;

  // aggregation: each wave owns 8 rows
  for (int q = 0; q < 8; ++q) {
    int lr = (wv << 3) + q;
    int r = r0 + lr;
    float2 a0 = {0.f, 0.f}, a1 = {0.f, 0.f}, a2 = {0.f, 0.f}, a3 = {0.f, 0.f};
    if (r < n) {
      int e0 = rp[r], e1 = rp[r + 1];
      int t = e0;
      for (; t + 4 <= e1; t += 4) {
        int s0 = col[t], s1 = col[t + 1], s2 = col[t + 2], s3 = col[t + 3];
        float w0 = nout[s0], w1 = nout[s1], w2 = nout[s2], w3 = nout[s3];
        float2 v0 = hv[s0 * 64 + lane];
        float2 v1 = hv[s1 * 64 + lane];
        float2 v2 = hv[s2 * 64 + lane];
        float2 v3 = hv[s3 * 64 + lane];
        a0.x += v0.x * w0; a0.y += v0.y * w0;
        a1.x += v1.x * w1; a1.y += v1.y * w1;
        a2.x += v2.x * w2; a2.y += v2.y * w2;
        a3.x += v3.x * w3; a3.y += v3.y * w3;
      }
      for (; t < e1; ++t) {
        int s0 = col[t];
        float w0 = nout[s0];
        float2 v0 = hv[s0 * 64 + lane];
        a0.x += v0.x * w0; a0.y += v0.y * w0;
      }
      float wi = nin[r];
      a0.x = (a0.x + a1.x + a2.x + a3.x) * wi;
      a0.y = (a0.y + a1.y + a2.y + a3.y) * wi;
    } else {
      a0.x = 0.f; a0.y = 0.f;
    }
    As[lr][2 * lane]     = a0.x;
    As[lr][2 * lane + 1] = a0.y;
  }
  __syncthreads();

  // GEMM: thread (tx=tid&31, ty=tid>>5) -> rows 4ty..+3, cols 4tx..+3
  int tx = tid & 31;
  int ty = tid >> 5;
  float acc[4][4];
  #pragma unroll
  for (int i = 0; i < 4; ++i)
    #pragma unroll
    for (int u = 0; u < 4; ++u) acc[i][u] = 0.f;

  int kr = tid >> 4, cs = tid & 15;   // W staging: k-row kr, 8-col seg cs
  for (int kc = 0; kc < 8; ++kc) {
    float4 w0 = *(const float4*)(W + (size_t)(kc * 16 + kr) * FD + cs * 8);
    float4 w1 = *(const float4*)(W + (size_t)(kc * 16 + kr) * FD + cs * 8 + 4);
    __syncthreads();                  // previous chunk fully consumed
    *(float4*)&Ws[kr][cs * 8]     = w0;
    *(float4*)&Ws[kr][cs * 8 + 4] = w1;
    __syncthreads();
    #pragma unroll
    for (int kk = 0; kk < 16; kk += 4) {
      float4 a[4];
      #pragma unroll
      for (int i = 0; i < 4; ++i)
        a[i] = *(const float4*)&As[4 * ty + i][kc * 16 + kk];
      #pragma unroll
      for (int t = 0; t < 4; ++t) {
        float4 wq = *(const float4*)&Ws[kk + t][4 * tx];
        #pragma unroll
        for (int i = 0; i < 4; ++i) {
          float av = (t == 0) ? a[i].x : (t == 1) ? a[i].y : (t == 2) ? a[i].z : a[i].w;
          acc[i][0] += av * wq.x;
          acc[i][1] += av * wq.y;
          acc[i][2] += av * wq.z;
          acc[i][3] += av * wq.w;
        }
      }
    }
  }

  float4 bv = *(const float4*)(bias + 4 * tx);
  #pragma unroll
  for (int i = 0; i < 4; ++i) {
    int row = r0 + 4 * ty + i;
    if (row < n) {
      float4 o;
      o.x = acc[i][0] + bv.x;
      o.y = acc[i][1] + bv.y;
      o.z = acc[i][2] + bv.z;
      o.w = acc[i][3] + bv.w;
      *(float4*)(out + (size_t)row * FD + 4 * tx) = o;
    }
  }
}

// ---------------- launch ----------------
extern "C" void kernel_launch(void* const* d_in, const int* in_sizes, int n_in,
                              void* d_out, int out_size, void* d_ws, size_t ws_size,
                              hipStream_t stream) {
  const float* x  = (const float*)d_in[0];
  const int* src  = (const int*)d_in[1];
  const int* dst  = (const int*)d_in[2];
  const float* W1 = (const float*)d_in[3];
  const float* b1 = (const float*)d_in[4];
  const float* W2 = (const float*)d_in[5];
  const float* b2 = (const float*)d_in[6];
  float* out = (float*)d_out;

  int n = in_sizes[0] / FD;      // 100000
  int e = in_sizes[1];           // 1600000
  int total = e + n;
  int nbuck = (n + BNODES - 1) >> SHIFT;   // 391

  char* ws = (char*)d_ws;
  size_t off = 0;
  auto alloc = [&](size_t bytes) -> void* {
    void* p = ws + off;
    off += (bytes + 255) / 256 * 256;
    return p;
  };
  float* h1   = (float*)alloc((size_t)n * FD * sizeof(float));  // 51.2 MB
  uint2* pairs = (uint2*)h1;   // alias: pairs (13.6 MB) dead before h1 is written
  int* col    = (int*)alloc((size_t)total * 4);                 // 6.8 MB
  int* rp     = (int*)alloc((size_t)(n + 1) * 4);
  float* nin  = (float*)alloc((size_t)n * 4);
  float* nout = (float*)alloc((size_t)n * 4);
  int* dego   = (int*)alloc((size_t)n * 4);
  int* bcnt   = (int*)alloc(512 * 4);
  int* bbase  = (int*)alloc(513 * 4);
  int* bcur   = (int*)alloc(512 * 4);

  hipMemsetAsync(dego, 0, (size_t)n * 4, stream);
  hipMemsetAsync(bcnt, 0, (size_t)nbuck * 4, stream);

  k_hist<<<256, 512, 0, stream>>>(dst, bcnt, e, n, nbuck);
  k_bscan<<<1, 512, 0, stream>>>(bcnt, bbase, bcur, nbuck, total);
  k_scatter<<<(total + CHUNK - 1) / CHUNK, ST, 0, stream>>>(
      src, dst, bcur, dego, pairs, e, n, nbuck);
  k_build<<<nbuck, 256, 0, stream>>>(pairs, bbase, dego, rp, col, nin, nout,
                                     n, nbuck, total);

  int lgrid = (n + 31) / 32;   // 3125
  k_layer<<<lgrid, 256, 0, stream>>>(x,  rp, col, nout, nin, W1, b1, h1,  n);
  k_layer<<<lgrid, 256, 0, stream>>>(h1, rp, col, nout, nin, W2, b2, out, n);
}

// Round 3
// 395.285 us; speedup vs baseline: 1.6185x; 1.1609x over previous
//
#include <hip/hip_runtime.h>

#define FD 128
#define SHIFT 8          // nodes per bucket
#define BNODES 256
#define CHUNK 2048       // edges per scatter block
#define ST 512           // scatter block threads

typedef unsigned int u32;
typedef unsigned short u16;

__device__ inline u16 f2bf(float f) {            // fp32 -> bf16 RNE
  u32 u = __float_as_uint(f);
  u += 0x7fffu + ((u >> 16) & 1u);
  return (u16)(u >> 16);
}

// ---------- pass 0: bucket histogram over dst (incl. self-loops) ----------
__global__ __launch_bounds__(512) void k_hist(const int* __restrict__ dst,
                                              int* __restrict__ bcnt,
                                              int e, int n, int nbuck) {
  __shared__ int sh[512];
  int tid = threadIdx.x;
  sh[tid] = 0;
  __syncthreads();
  int total = e + n;
  for (int t = blockIdx.x * blockDim.x + tid; t < total; t += gridDim.x * blockDim.x) {
    int d = (t < e) ? dst[t] : (t - e);
    atomicAdd(&sh[d >> SHIFT], 1);
  }
  __syncthreads();
  if (tid < nbuck && sh[tid]) atomicAdd(&bcnt[tid], sh[tid]);
}

// ---------- pass 1: scan buckets ----------
__global__ __launch_bounds__(512) void k_bscan(const int* __restrict__ bcnt,
                                               int* __restrict__ bbase,
                                               int* __restrict__ bcur,
                                               int nbuck, int total) {
  __shared__ int sh[512];
  int tid = threadIdx.x;
  int v = (tid < nbuck) ? bcnt[tid] : 0;
  sh[tid] = v;
  __syncthreads();
  for (int off = 1; off < 512; off <<= 1) {
    int add = (tid >= off) ? sh[tid - off] : 0;
    __syncthreads();
    sh[tid] += add;
    __syncthreads();
  }
  if (tid < nbuck) { int ex = sh[tid] - v; bbase[tid] = ex; bcur[tid] = ex; }
  if (tid == 0) bbase[nbuck] = total;
}

// ---------- pass 2: locality-aware scatter of packed (ldst,src) by bucket ----------
__global__ __launch_bounds__(ST) void k_scatter(
    const int* __restrict__ src, const int* __restrict__ dst,
    int* __restrict__ bcur, int* __restrict__ dego,
    u32* __restrict__ pairs, int e, int n, int nbuck) {
  __shared__ int hist[512];
  __shared__ int incl[512];
  __shared__ int excl[512];
  __shared__ int gbase[512];
  __shared__ u32 stgv[CHUNK];
  __shared__ u16 stgb[CHUNK];
  int tid = threadIdx.x;
  int c0 = blockIdx.x * CHUNK;
  int total = e + n;
  hist[tid] = 0;
  __syncthreads();
  u32 pv_[4]; int b_[4]; bool v_[4];
  #pragma unroll
  for (int i = 0; i < 4; ++i) {
    int t = c0 + i * ST + tid;
    v_[i] = (t < total);
    pv_[i] = 0; b_[i] = 0;
    if (v_[i]) {
      int s, d;
      if (t < e) { s = src[t]; d = dst[t]; atomicAdd(&dego[s], 1); }
      else       { s = t - e;  d = s; }
      pv_[i] = ((u32)(d & (BNODES - 1)) << 24) | (u32)s;
      b_[i] = d >> SHIFT;
      atomicAdd(&hist[b_[i]], 1);
    }
  }
  __syncthreads();
  int h = hist[tid];
  incl[tid] = h;
  __syncthreads();
  for (int off = 1; off < 512; off <<= 1) {
    int add = (tid >= off) ? incl[tid - off] : 0;
    __syncthreads();
    incl[tid] += add;
    __syncthreads();
  }
  excl[tid] = incl[tid] - h;
  if (tid < nbuck && h > 0) gbase[tid] = atomicAdd(&bcur[tid], h);
  __syncthreads();
  hist[tid] = excl[tid];       // local rank cursor
  __syncthreads();
  #pragma unroll
  for (int i = 0; i < 4; ++i) {
    if (v_[i]) {
      int p = atomicAdd(&hist[b_[i]], 1);
      stgv[p] = pv_[i];
      stgb[p] = (u16)b_[i];
    }
  }
  __syncthreads();
  int V = min(CHUNK, total - c0);
  for (int j = tid; j < V; j += ST) {
    int b = stgb[j];
    pairs[gbase[b] + (j - excl[b])] = stgv[j];   // contiguous runs per bucket
  }
}

// ---------- pass 3: per-bucket CSR finalize (rp, norms, col) ----------
__global__ __launch_bounds__(256) void k_build(
    const u32* __restrict__ pairs, const int* __restrict__ bbase,
    const int* __restrict__ dego,
    int* __restrict__ rp, int* __restrict__ col,
    float* __restrict__ nin, float* __restrict__ nout,
    int n, int nbuck, int total) {
  __shared__ int cnt[256];
  __shared__ int off_[256];
  __shared__ int cur[256];
  int tid = threadIdx.x;
  int b = blockIdx.x;
  int base = bbase[b], end = bbase[b + 1];
  int node0 = b << SHIFT;
  cnt[tid] = 0;
  __syncthreads();
  for (int t = base + tid; t < end; t += 256)
    atomicAdd(&cnt[(int)(pairs[t] >> 24)], 1);
  __syncthreads();
  int c = cnt[tid];
  off_[tid] = c;
  __syncthreads();
  for (int off = 1; off < 256; off <<= 1) {
    int add = (tid >= off) ? off_[tid - off] : 0;
    __syncthreads();
    off_[tid] += add;
    __syncthreads();
  }
  int ex = off_[tid] - c;
  int node = node0 + tid;
  if (node < n) {
    rp[node] = base + ex;
    nin[node] = rsqrtf((float)c);              // in-degree incl self-loop
    nout[node] = rsqrtf((float)(dego[node] + 1));
  }
  if (b == nbuck - 1 && tid == 0) rp[n] = total;
  cur[tid] = ex;
  __syncthreads();
  for (int t = base + tid; t < end; t += 256) {
    u32 pr = pairs[t];
    int p = atomicAdd(&cur[(int)(pr >> 24)], 1);
    col[base + p] = (int)(pr & 0xFFFFFFu);
  }
}

// ---------- pre-scale x by norm_out and convert to bf16 ----------
__global__ __launch_bounds__(256) void k_prescale(
    const float* __restrict__ x, const float* __restrict__ nout,
    u32* __restrict__ xs, int n) {
  int tot = n * 64;   // float2 elements
  const float2* xv = (const float2*)x;
  for (int idx = blockIdx.x * blockDim.x + threadIdx.x; idx < tot;
       idx += gridDim.x * blockDim.x) {
    int row = idx >> 6;
    float w = nout[row];
    float2 v = xv[idx];
    xs[idx] = (u32)f2bf(v.x * w) | ((u32)f2bf(v.y * w) << 16);
  }
}

// ---------- fused layer: bf16 gather-aggregate 32 rows to LDS, then fp32 GEMM ----------
// input hs = bf16(nout[s]*h[s]); out = (nin[r]*sum hs[s]) @ W + bias
// mode 0: write fp32 to fout ; mode 1: write bf16(nout[r]*val) to hsout
__global__ __launch_bounds__(256) void k_layer(
    const u32* __restrict__ hs, const int* __restrict__ rp,
    const int* __restrict__ col, const float* __restrict__ nin,
    const float* __restrict__ nout,
    const float* __restrict__ W, const float* __restrict__ bias,
    float* __restrict__ fout, u32* __restrict__ hsout,
    int n, int mode) {
  __shared__ float As[32][132];
  __shared__ float Ws[16][132];
  int tid = threadIdx.x;
  int lane = tid & 63;
  int wv = tid >> 6;
  int r0 = blockIdx.x * 32;

  // aggregation: each wave owns 8 rows; 8 edge-gathers in flight
  for (int q = 0; q < 8; ++q) {
    int lr = (wv << 3) + q;
    int r = r0 + lr;
    float2 a0 = {0.f, 0.f}, a1 = {0.f, 0.f}, a2 = {0.f, 0.f}, a3 = {0.f, 0.f};
    if (r < n) {
      int e0 = rp[r], e1 = rp[r + 1];   // e1 > e0 always (self-loop)
      for (int t = e0; t < e1; t += 8) {
        int s[8]; u32 u[8];
        #pragma unroll
        for (int i = 0; i < 8; ++i) {
          int tt = (t + i < e1) ? (t + i) : (e1 - 1);   // wave-uniform clamp
          s[i] = col[tt];
        }
        #pragma unroll
        for (int i = 0; i < 8; ++i) u[i] = hs[s[i] * 64 + lane];
        #pragma unroll
        for (int i = 0; i < 8; ++i) {
          if (t + i < e1) {                              // wave-uniform predicate
            float lo = __uint_as_float(u[i] << 16);
            float hi = __uint_as_float(u[i] & 0xFFFF0000u);
            float2* ac = (i & 2) ? ((i & 1) ? &a3 : &a2) : ((i & 1) ? &a1 : &a0);
            ac->x += lo; ac->y += hi;
          }
        }
      }
      float wi = nin[r];
      a0.x = (a0.x + a1.x + a2.x + a3.x) * wi;
      a0.y = (a0.y + a1.y + a2.y + a3.y) * wi;
    } else {
      a0.x = 0.f; a0.y = 0.f;
    }
    As[lr][2 * lane]     = a0.x;
    As[lr][2 * lane + 1] = a0.y;
  }
  __syncthreads();

  // GEMM: thread (tx=tid&31, ty=tid>>5) -> rows 4ty..+3, cols 4tx..+3
  int tx = tid & 31;
  int ty = tid >> 5;
  float acc[4][4];
  #pragma unroll
  for (int i = 0; i < 4; ++i)
    #pragma unroll
    for (int u = 0; u < 4; ++u) acc[i][u] = 0.f;

  int kr = tid >> 4, cs = tid & 15;   // W staging: k-row kr, 8-col seg cs
  for (int kc = 0; kc < 8; ++kc) {
    float4 w0 = *(const float4*)(W + (size_t)(kc * 16 + kr) * FD + cs * 8);
    float4 w1 = *(const float4*)(W + (size_t)(kc * 16 + kr) * FD + cs * 8 + 4);
    __syncthreads();
    *(float4*)&Ws[kr][cs * 8]     = w0;
    *(float4*)&Ws[kr][cs * 8 + 4] = w1;
    __syncthreads();
    #pragma unroll
    for (int kk = 0; kk < 16; kk += 4) {
      float4 a[4];
      #pragma unroll
      for (int i = 0; i < 4; ++i)
        a[i] = *(const float4*)&As[4 * ty + i][kc * 16 + kk];
      #pragma unroll
      for (int t = 0; t < 4; ++t) {
        float4 wq = *(const float4*)&Ws[kk + t][4 * tx];
        #pragma unroll
        for (int i = 0; i < 4; ++i) {
          float av = (t == 0) ? a[i].x : (t == 1) ? a[i].y : (t == 2) ? a[i].z : a[i].w;
          acc[i][0] += av * wq.x;
          acc[i][1] += av * wq.y;
          acc[i][2] += av * wq.z;
          acc[i][3] += av * wq.w;
        }
      }
    }
  }

  float4 bv = *(const float4*)(bias + 4 * tx);
  #pragma unroll
  for (int i = 0; i < 4; ++i) {
    int row = r0 + 4 * ty + i;
    if (row < n) {
      float o0 = acc[i][0] + bv.x;
      float o1 = acc[i][1] + bv.y;
      float o2 = acc[i][2] + bv.z;
      float o3 = acc[i][3] + bv.w;
      if (mode == 0) {
        *(float4*)(fout + (size_t)row * FD + 4 * tx) = make_float4(o0, o1, o2, o3);
      } else {
        float w = nout[row];
        u32 p0 = (u32)f2bf(o0 * w) | ((u32)f2bf(o1 * w) << 16);
        u32 p1 = (u32)f2bf(o2 * w) | ((u32)f2bf(o3 * w) << 16);
        *(uint2*)(hsout + (size_t)row * 64 + 2 * tx) = make_uint2(p0, p1);
      }
    }
  }
}

// ---------------- launch ----------------
extern "C" void kernel_launch(void* const* d_in, const int* in_sizes, int n_in,
                              void* d_out, int out_size, void* d_ws, size_t ws_size,
                              hipStream_t stream) {
  const float* x  = (const float*)d_in[0];
  const int* src  = (const int*)d_in[1];
  const int* dst  = (const int*)d_in[2];
  const float* W1 = (const float*)d_in[3];
  const float* b1 = (const float*)d_in[4];
  const float* W2 = (const float*)d_in[5];
  const float* b2 = (const float*)d_in[6];
  float* out = (float*)d_out;

  int n = in_sizes[0] / FD;      // 100000
  int e = in_sizes[1];           // 1600000
  int total = e + n;
  int nbuck = (n + BNODES - 1) >> SHIFT;   // 391

  char* ws = (char*)d_ws;
  size_t off = 0;
  auto alloc = [&](size_t bytes) -> void* {
    void* p = ws + off;
    off += (bytes + 255) / 256 * 256;
    return p;
  };
  u32* h1s  = (u32*)alloc((size_t)n * 64 * 4);   // 25.6 MB (bf16 h1, pre-scaled)
  u32* pairs = h1s;                               // alias: pairs (6.8 MB) dead before h1s
  u32* xs   = (u32*)alloc((size_t)n * 64 * 4);   // 25.6 MB (bf16 x, pre-scaled)
  int* col  = (int*)alloc((size_t)total * 4);    // 6.8 MB
  int* rp   = (int*)alloc((size_t)(n + 1) * 4);
  float* nin  = (float*)alloc((size_t)n * 4);
  float* nout = (float*)alloc((size_t)n * 4);
  int* dego   = (int*)alloc((size_t)n * 4);
  int* bcnt   = (int*)alloc(512 * 4);
  int* bbase  = (int*)alloc(513 * 4);
  int* bcur   = (int*)alloc(512 * 4);

  hipMemsetAsync(dego, 0, (size_t)n * 4, stream);
  hipMemsetAsync(bcnt, 0, (size_t)nbuck * 4, stream);

  k_hist<<<256, 512, 0, stream>>>(dst, bcnt, e, n, nbuck);
  k_bscan<<<1, 512, 0, stream>>>(bcnt, bbase, bcur, nbuck, total);
  k_scatter<<<(total + CHUNK - 1) / CHUNK, ST, 0, stream>>>(
      src, dst, bcur, dego, pairs, e, n, nbuck);
  k_build<<<nbuck, 256, 0, stream>>>(pairs, bbase, dego, rp, col, nin, nout,
                                     n, nbuck, total);
  k_prescale<<<2048, 256, 0, stream>>>(x, nout, xs, n);

  int lgrid = (n + 31) / 32;   // 3125
  k_layer<<<lgrid, 256, 0, stream>>>(xs,  rp, col, nin, nout, W1, b1,
                                     nullptr, h1s, n, 1);
  k_layer<<<lgrid, 256, 0, stream>>>(h1s, rp, col, nin, nout, W2, b2,
                                     out, nullptr, n, 0);
}

// Round 4
// 361.229 us; speedup vs baseline: 1.7711x; 1.0943x over previous
//
#include <hip/hip_runtime.h>

#define FD 128
#define SHIFT 8          // nodes per bucket
#define BNODES 256
#define CHUNK 2048       // edges per scatter block
#define ST 512           // scatter block threads

typedef unsigned int u32;
typedef unsigned short u16;
typedef __attribute__((ext_vector_type(8))) short short8;   // 8 bf16 (4 VGPR)
typedef __attribute__((ext_vector_type(4))) float f32x4;
typedef __attribute__((ext_vector_type(4))) u32 u32x4;

__device__ inline u16 f2bf(float f) {            // fp32 -> bf16 RNE
  u32 u = __float_as_uint(f);
  u += 0x7fffu + ((u >> 16) & 1u);
  return (u16)(u >> 16);
}
__device__ inline float bf2f(u16 h) { return __uint_as_float((u32)h << 16); }

// ---------- pass 0: bucket histogram over dst (incl. self-loops) ----------
__global__ __launch_bounds__(512) void k_hist(const int* __restrict__ dst,
                                              int* __restrict__ bcnt,
                                              int e, int n, int nbuck) {
  __shared__ int sh[512];
  int tid = threadIdx.x;
  sh[tid] = 0;
  __syncthreads();
  int total = e + n;
  for (int t = blockIdx.x * blockDim.x + tid; t < total; t += gridDim.x * blockDim.x) {
    int d = (t < e) ? dst[t] : (t - e);
    atomicAdd(&sh[d >> SHIFT], 1);
  }
  __syncthreads();
  if (tid < nbuck && sh[tid]) atomicAdd(&bcnt[tid], sh[tid]);
}

// ---------- pass 1: scan buckets ----------
__global__ __launch_bounds__(512) void k_bscan(const int* __restrict__ bcnt,
                                               int* __restrict__ bbase,
                                               int* __restrict__ bcur,
                                               int nbuck, int total) {
  __shared__ int sh[512];
  int tid = threadIdx.x;
  int v = (tid < nbuck) ? bcnt[tid] : 0;
  sh[tid] = v;
  __syncthreads();
  for (int off = 1; off < 512; off <<= 1) {
    int add = (tid >= off) ? sh[tid - off] : 0;
    __syncthreads();
    sh[tid] += add;
    __syncthreads();
  }
  if (tid < nbuck) { int ex = sh[tid] - v; bbase[tid] = ex; bcur[tid] = ex; }
  if (tid == 0) bbase[nbuck] = total;
}

// ---------- pass 2: locality-aware scatter of packed (ldst,src) by bucket ----------
__global__ __launch_bounds__(ST) void k_scatter(
    const int* __restrict__ src, const int* __restrict__ dst,
    int* __restrict__ bcur, int* __restrict__ dego,
    u32* __restrict__ pairs, int e, int n, int nbuck) {
  __shared__ int hist[512];
  __shared__ int incl[512];
  __shared__ int excl[512];
  __shared__ int gbase[512];
  __shared__ u32 stgv[CHUNK];
  __shared__ u16 stgb[CHUNK];
  int tid = threadIdx.x;
  int c0 = blockIdx.x * CHUNK;
  int total = e + n;
  hist[tid] = 0;
  __syncthreads();
  u32 pv_[4]; int b_[4]; bool v_[4];
  #pragma unroll
  for (int i = 0; i < 4; ++i) {
    int t = c0 + i * ST + tid;
    v_[i] = (t < total);
    pv_[i] = 0; b_[i] = 0;
    if (v_[i]) {
      int s, d;
      if (t < e) { s = src[t]; d = dst[t]; atomicAdd(&dego[s], 1); }
      else       { s = t - e;  d = s; }
      pv_[i] = ((u32)(d & (BNODES - 1)) << 24) | (u32)s;
      b_[i] = d >> SHIFT;
      atomicAdd(&hist[b_[i]], 1);
    }
  }
  __syncthreads();
  int h = hist[tid];
  incl[tid] = h;
  __syncthreads();
  for (int off = 1; off < 512; off <<= 1) {
    int add = (tid >= off) ? incl[tid - off] : 0;
    __syncthreads();
    incl[tid] += add;
    __syncthreads();
  }
  excl[tid] = incl[tid] - h;
  if (tid < nbuck && h > 0) gbase[tid] = atomicAdd(&bcur[tid], h);
  __syncthreads();
  hist[tid] = excl[tid];       // local rank cursor
  __syncthreads();
  #pragma unroll
  for (int i = 0; i < 4; ++i) {
    if (v_[i]) {
      int p = atomicAdd(&hist[b_[i]], 1);
      stgv[p] = pv_[i];
      stgb[p] = (u16)b_[i];
    }
  }
  __syncthreads();
  int V = min(CHUNK, total - c0);
  for (int j = tid; j < V; j += ST) {
    int b = stgb[j];
    pairs[gbase[b] + (j - excl[b])] = stgv[j];   // contiguous runs per bucket
  }
}

// ---------- pass 3: per-bucket CSR finalize (rp, norms, col) ----------
__global__ __launch_bounds__(256) void k_build(
    const u32* __restrict__ pairs, const int* __restrict__ bbase,
    const int* __restrict__ dego,
    int* __restrict__ rp, int* __restrict__ col,
    float* __restrict__ nin, float* __restrict__ nout,
    int n, int nbuck, int total) {
  __shared__ int cnt[256];
  __shared__ int off_[256];
  __shared__ int cur[256];
  int tid = threadIdx.x;
  int b = blockIdx.x;
  int base = bbase[b], end = bbase[b + 1];
  int node0 = b << SHIFT;
  cnt[tid] = 0;
  __syncthreads();
  for (int t = base + tid; t < end; t += 256)
    atomicAdd(&cnt[(int)(pairs[t] >> 24)], 1);
  __syncthreads();
  int c = cnt[tid];
  off_[tid] = c;
  __syncthreads();
  for (int off = 1; off < 256; off <<= 1) {
    int add = (tid >= off) ? off_[tid - off] : 0;
    __syncthreads();
    off_[tid] += add;
    __syncthreads();
  }
  int ex = off_[tid] - c;
  int node = node0 + tid;
  if (node < n) {
    rp[node] = base + ex;
    nin[node] = rsqrtf((float)c);              // in-degree incl self-loop
    nout[node] = rsqrtf((float)(dego[node] + 1));
  }
  if (b == nbuck - 1 && tid == 0) rp[n] = total;
  cur[tid] = ex;
  __syncthreads();
  for (int t = base + tid; t < end; t += 256) {
    u32 pr = pairs[t];
    int p = atomicAdd(&cur[(int)(pr >> 24)], 1);
    col[base + p] = (int)(pr & 0xFFFFFFu);
  }
}

// ---------- pre-scale x by norm_out and convert to bf16 ----------
__global__ __launch_bounds__(256) void k_prescale(
    const float* __restrict__ x, const float* __restrict__ nout,
    u32* __restrict__ xs, int n) {
  int tot = n * 64;   // float2 elements
  const float2* xv = (const float2*)x;
  for (int idx = blockIdx.x * blockDim.x + threadIdx.x; idx < tot;
       idx += gridDim.x * blockDim.x) {
    int row = idx >> 6;
    float w = nout[row];
    float2 v = xv[idx];
    xs[idx] = (u32)f2bf(v.x * w) | ((u32)f2bf(v.y * w) << 16);
  }
}

// ---------- W -> fragment-ordered split-bf16 (hi/lo planes) ----------
// frag f = nt*4+kt; lane l holds W[kt*32 + (l>>4)*8 + j][nt*16 + (l&15)], j=0..7
// packed as 4 u32 per lane (j pairs), contiguous per lane for dwordx4 loads.
__global__ void k_prepw(const float* __restrict__ W, u32* __restrict__ wfhi,
                        u32* __restrict__ wflo) {
  int i = blockIdx.x * 256 + threadIdx.x;   // 8192 u32 per plane
  if (i >= 8192) return;
  int m = i & 3, l = (i >> 2) & 63, f = i >> 8;
  int kt = f & 3, nt = f >> 2;
  int k0 = kt * 32 + ((l >> 4) << 3) + 2 * m;
  int c = nt * 16 + (l & 15);
  float w0 = W[k0 * FD + c], w1 = W[(k0 + 1) * FD + c];
  u16 h0 = f2bf(w0), h1 = f2bf(w1);
  u16 l0 = f2bf(w0 - bf2f(h0)), l1 = f2bf(w1 - bf2f(h1));
  wfhi[i] = (u32)h0 | ((u32)h1 << 16);
  wflo[i] = (u32)l0 | ((u32)l1 << 16);
}

// ---------- aggregation: one wave per dst row, bf16 in, split-bf16 out ----------
// a[r] = nin[r] * sum_{s in N(r)} hs[s]; write hi/lo planes with XOR-swizzled
// within-row 16B-chunk order (so GEMM's LDS frag reads are conflict-free).
__global__ __launch_bounds__(256) void k_agg(
    const u32* __restrict__ hs, const int* __restrict__ rp,
    const int* __restrict__ col, const float* __restrict__ nin,
    u32* __restrict__ ahi, u32* __restrict__ alo, int n) {
  int wid = (blockIdx.x * 256 + threadIdx.x) >> 6;
  int lane = threadIdx.x & 63;
  if (wid >= n) return;
  int e0 = rp[wid], e1 = rp[wid + 1];   // e1 > e0 (self-loop)
  float ax[4] = {0.f, 0.f, 0.f, 0.f};
  float ay[4] = {0.f, 0.f, 0.f, 0.f};
  for (int t = e0; t < e1; t += 8) {
    int s[8]; u32 u[8];
    #pragma unroll
    for (int i = 0; i < 8; ++i) {
      int tt = (t + i < e1) ? (t + i) : (e1 - 1);   // wave-uniform clamp
      s[i] = col[tt];
    }
    #pragma unroll
    for (int i = 0; i < 8; ++i) u[i] = hs[s[i] * 64 + lane];
    #pragma unroll
    for (int i = 0; i < 8; ++i) {
      if (t + i < e1) {                              // wave-uniform predicate
        ax[i & 3] += __uint_as_float(u[i] << 16);
        ay[i & 3] += __uint_as_float(u[i] & 0xFFFF0000u);
      }
    }
  }
  float wi = nin[wid];
  float vx = (ax[0] + ax[1] + ax[2] + ax[3]) * wi;
  float vy = (ay[0] + ay[1] + ay[2] + ay[3]) * wi;
  u16 hx = f2bf(vx), hy = f2bf(vy);
  u16 lx = f2bf(vx - bf2f(hx)), ly = f2bf(vy - bf2f(hy));
  int idx = wid * 64 + (lane ^ ((wid & 7) << 2));   // 16B-chunk XOR swizzle
  ahi[idx] = (u32)hx | ((u32)hy << 16);
  alo[idx] = (u32)lx | ((u32)ly << 16);
}

// ---------- MFMA GEMM: out[64xFD tile] = (Ahi+Alo) @ (Whi+Wlo) + bias ----------
// 256 thr = 4 waves; wave mt does rows r0+16mt..+15. 3 MFMA products per ktile
// (hi*hi + hi*lo + lo*hi). mode 0: fp32 out. mode 1: bf16(nout*val) for next agg.
__global__ __launch_bounds__(256) void k_gemm(
    const u32* __restrict__ ahi, const u32* __restrict__ alo,
    const u32* __restrict__ wfhi, const u32* __restrict__ wflo,
    const float* __restrict__ bias, const float* __restrict__ nout,
    float* __restrict__ fout, u16* __restrict__ hsout, int n, int mode) {
  __shared__ u32 Ah[4096];   // 64 rows x 256B (swizzled), 16 KB
  __shared__ u32 Al[4096];
  int tid = threadIdx.x;
  int lane = tid & 63;
  int mt = tid >> 6;
  int r0 = blockIdx.x * 64;

  // stage A tile (straight copy; swizzle already baked into global layout)
  const u32x4* gh = (const u32x4*)(ahi + (size_t)r0 * 64);
  const u32x4* gl = (const u32x4*)(alo + (size_t)r0 * 64);
  u32x4* sh_ = (u32x4*)Ah;
  u32x4* sl_ = (u32x4*)Al;
  #pragma unroll
  for (int t = 0; t < 4; ++t) {
    sh_[t * 256 + tid] = gh[t * 256 + tid];
    sl_[t * 256 + tid] = gl[t * 256 + tid];
  }
  __syncthreads();

  // A fragments: lane l -> row mt*16+(l&15), k-chunk (l>>4)*8 within ktile
  short8 afh[4], afl[4];
  int arow = mt * 16 + (lane & 15);
  #pragma unroll
  for (int kt = 0; kt < 4; ++kt) {
    int boff = arow * 256 + ((kt * 64 + (lane >> 4) * 16) ^ ((arow & 7) << 4));
    afh[kt] = *(const short8*)((const char*)Ah + boff);
    afl[kt] = *(const short8*)((const char*)Al + boff);
  }

  for (int nt = 0; nt < 8; ++nt) {
    f32x4 acc = {0.f, 0.f, 0.f, 0.f};
    #pragma unroll
    for (int kt = 0; kt < 4; ++kt) {
      int f = nt * 4 + kt;
      short8 wh = *(const short8*)(wfhi + (size_t)(f * 64 + lane) * 4);
      short8 wl = *(const short8*)(wflo + (size_t)(f * 64 + lane) * 4);
      acc = __builtin_amdgcn_mfma_f32_16x16x32_bf16(afh[kt], wh, acc, 0, 0, 0);
      acc = __builtin_amdgcn_mfma_f32_16x16x32_bf16(afh[kt], wl, acc, 0, 0, 0);
      acc = __builtin_amdgcn_mfma_f32_16x16x32_bf16(afl[kt], wh, acc, 0, 0, 0);
    }
    int c = nt * 16 + (lane & 15);
    float bv = bias[c];
    int rbase = r0 + mt * 16 + (lane >> 4) * 4;   // C/D: col=lane&15, row=(lane>>4)*4+j
    if (mode == 0) {
      #pragma unroll
      for (int j = 0; j < 4; ++j) {
        int row = rbase + j;
        if (row < n) fout[(size_t)row * FD + c] = acc[j] + bv;
      }
    } else {
      #pragma unroll
      for (int j = 0; j < 4; ++j) {
        int row = rbase + j;
        if (row < n) hsout[(size_t)row * FD + c] = f2bf((acc[j] + bv) * nout[row]);
      }
    }
  }
}

// ---------------- launch ----------------
extern "C" void kernel_launch(void* const* d_in, const int* in_sizes, int n_in,
                              void* d_out, int out_size, void* d_ws, size_t ws_size,
                              hipStream_t stream) {
  const float* x  = (const float*)d_in[0];
  const int* src  = (const int*)d_in[1];
  const int* dst  = (const int*)d_in[2];
  const float* W1 = (const float*)d_in[3];
  const float* b1 = (const float*)d_in[4];
  const float* W2 = (const float*)d_in[5];
  const float* b2 = (const float*)d_in[6];
  float* out = (float*)d_out;

  int n = in_sizes[0] / FD;      // 100000
  int e = in_sizes[1];           // 1600000
  int total = e + n;
  int nbuck = (n + BNODES - 1) >> SHIFT;   // 391

  char* ws = (char*)d_ws;
  size_t off = 0;
  auto alloc = [&](size_t bytes) -> void* {
    void* p = ws + off;
    off += (bytes + 255) / 256 * 256;
    return p;
  };
  // shared region: pairs (build) -> xs (prescale/agg1) -> h1s (gemm1/agg2)
  u32* shared_ = (u32*)alloc((size_t)n * 64 * 4);    // 25.6 MB
  u32* pairs = shared_;
  u32* xs    = shared_;
  u16* h1s   = (u16*)shared_;
  u32* ahi   = (u32*)alloc((size_t)(n + 64) * 64 * 4);  // 25.6 MB
  u32* alo   = (u32*)alloc((size_t)(n + 64) * 64 * 4);  // 25.6 MB
  int* col   = (int*)alloc((size_t)total * 4);          // 6.8 MB
  int* rp    = (int*)alloc((size_t)(n + 1) * 4);
  float* nin  = (float*)alloc((size_t)n * 4);
  float* nout = (float*)alloc((size_t)n * 4);
  int* dego   = (int*)alloc((size_t)n * 4);
  int* bcnt   = (int*)alloc(512 * 4);
  int* bbase  = (int*)alloc(513 * 4);
  int* bcur   = (int*)alloc(512 * 4);
  u32* wf1hi  = (u32*)alloc(8192 * 4);
  u32* wf1lo  = (u32*)alloc(8192 * 4);
  u32* wf2hi  = (u32*)alloc(8192 * 4);
  u32* wf2lo  = (u32*)alloc(8192 * 4);

  hipMemsetAsync(dego, 0, (size_t)n * 4, stream);
  hipMemsetAsync(bcnt, 0, (size_t)nbuck * 4, stream);

  k_hist<<<256, 512, 0, stream>>>(dst, bcnt, e, n, nbuck);
  k_bscan<<<1, 512, 0, stream>>>(bcnt, bbase, bcur, nbuck, total);
  k_scatter<<<(total + CHUNK - 1) / CHUNK, ST, 0, stream>>>(
      src, dst, bcur, dego, pairs, e, n, nbuck);
  k_build<<<nbuck, 256, 0, stream>>>(pairs, bbase, dego, rp, col, nin, nout,
                                     n, nbuck, total);
  k_prepw<<<32, 256, 0, stream>>>(W1, wf1hi, wf1lo);
  k_prepw<<<32, 256, 0, stream>>>(W2, wf2hi, wf2lo);
  k_prescale<<<2048, 256, 0, stream>>>(x, nout, xs, n);

  int agrid = (n + 3) / 4;       // 1 wave per row
  int ggrid = (n + 63) / 64;
  // layer 1
  k_agg<<<agrid, 256, 0, stream>>>(xs, rp, col, nin, ahi, alo, n);
  k_gemm<<<ggrid, 256, 0, stream>>>(ahi, alo, wf1hi, wf1lo, b1, nout,
                                    nullptr, h1s, n, 1);
  // layer 2
  k_agg<<<agrid, 256, 0, stream>>>((const u32*)h1s, rp, col, nin, ahi, alo, n);
  k_gemm<<<ggrid, 256, 0, stream>>>(ahi, alo, wf2hi, wf2lo, b2, nout,
                                    out, nullptr, n, 0);
}

// Round 5
// 351.434 us; speedup vs baseline: 1.8205x; 1.0279x over previous
//
#include <hip/hip_runtime.h>

#define FD 128
#define SHIFT 10         // nodes per bucket = 1024
#define BNODES 1024
#define NBK 128          // padded bucket-array size (98 used)
#define CHUNK 4096       // edges per scatter block
#define ST 512           // scatter block threads

typedef unsigned int u32;
typedef unsigned short u16;
typedef __attribute__((ext_vector_type(8))) short short8;   // 8 bf16 (4 VGPR)
typedef __attribute__((ext_vector_type(4))) float f32x4;
typedef __attribute__((ext_vector_type(4))) u32 u32x4;

__device__ inline u16 f2bf(float f) {            // fp32 -> bf16 RNE
  u32 u = __float_as_uint(f);
  u += 0x7fffu + ((u >> 16) & 1u);
  return (u16)(u >> 16);
}
__device__ inline float bf2f(u16 h) { return __uint_as_float((u32)h << 16); }

// ---------- pass 0: bucket histogram over dst (incl. self-loops) ----------
__global__ __launch_bounds__(512) void k_hist(const int* __restrict__ dst,
                                              int* __restrict__ bcnt,
                                              int e, int n, int nbuck) {
  __shared__ int sh[NBK];
  int tid = threadIdx.x;
  if (tid < NBK) sh[tid] = 0;
  __syncthreads();
  int total = e + n;
  for (int t = blockIdx.x * blockDim.x + tid; t < total; t += gridDim.x * blockDim.x) {
    int d = (t < e) ? dst[t] : (t - e);
    atomicAdd(&sh[d >> SHIFT], 1);
  }
  __syncthreads();
  if (tid < nbuck && sh[tid]) atomicAdd(&bcnt[tid], sh[tid]);
}

// ---------- pass 1: scan buckets ----------
__global__ __launch_bounds__(NBK) void k_bscan(const int* __restrict__ bcnt,
                                               int* __restrict__ bbase,
                                               int* __restrict__ bcur,
                                               int nbuck, int total) {
  __shared__ int sh[NBK];
  int tid = threadIdx.x;
  int v = (tid < nbuck) ? bcnt[tid] : 0;
  sh[tid] = v;
  __syncthreads();
  for (int off = 1; off < NBK; off <<= 1) {
    int add = (tid >= off) ? sh[tid - off] : 0;
    __syncthreads();
    sh[tid] += add;
    __syncthreads();
  }
  if (tid < nbuck) { int ex = sh[tid] - v; bbase[tid] = ex; bcur[tid] = ex; }
  if (tid == 0) bbase[nbuck] = total;
}

// ---------- pass 2: locality-aware scatter of packed (ldst,src) by bucket ----------
// pack: local_dst(10b) << 22 | src(22b)
__global__ __launch_bounds__(ST) void k_scatter(
    const int* __restrict__ src, const int* __restrict__ dst,
    int* __restrict__ bcur, int* __restrict__ dego,
    u32* __restrict__ pairs, int e, int n, int nbuck) {
  __shared__ int hist[NBK];
  __shared__ int incl[NBK];
  __shared__ int excl[NBK];
  __shared__ int gbase[NBK];
  __shared__ int rank[NBK];
  __shared__ u32 stgv[CHUNK];
  __shared__ u16 stgb[CHUNK];
  int tid = threadIdx.x;
  int c0 = blockIdx.x * CHUNK;
  int total = e + n;
  if (tid < NBK) hist[tid] = 0;
  __syncthreads();
  u32 pv_[8]; int b_[8]; bool v_[8];
  #pragma unroll
  for (int i = 0; i < 8; ++i) {
    int t = c0 + i * ST + tid;
    v_[i] = (t < total);
    pv_[i] = 0; b_[i] = 0;
    if (v_[i]) {
      int s, d;
      if (t < e) { s = src[t]; d = dst[t]; atomicAdd(&dego[s], 1); }
      else       { s = t - e;  d = s; }
      pv_[i] = ((u32)(d & (BNODES - 1)) << 22) | (u32)s;
      b_[i] = d >> SHIFT;
      atomicAdd(&hist[b_[i]], 1);
    }
  }
  __syncthreads();
  int h = 0;
  if (tid < NBK) { h = hist[tid]; incl[tid] = h; }
  __syncthreads();
  for (int off = 1; off < NBK; off <<= 1) {
    int add = 0;
    if (tid < NBK && tid >= off) add = incl[tid - off];
    __syncthreads();
    if (tid < NBK) incl[tid] += add;
    __syncthreads();
  }
  if (tid < NBK) {
    int ex = incl[tid] - h;
    excl[tid] = ex;
    rank[tid] = ex;
    if (tid < nbuck && h > 0) gbase[tid] = atomicAdd(&bcur[tid], h);
  }
  __syncthreads();
  #pragma unroll
  for (int i = 0; i < 8; ++i) {
    if (v_[i]) {
      int p = atomicAdd(&rank[b_[i]], 1);
      stgv[p] = pv_[i];
      stgb[p] = (u16)b_[i];
    }
  }
  __syncthreads();
  int V = min(CHUNK, total - c0);
  for (int j = tid; j < V; j += ST) {
    int b = stgb[j];
    pairs[gbase[b] + (j - excl[b])] = stgv[j];   // ~168B contiguous runs per bucket
  }
}

// ---------- pass 3: per-bucket CSR finalize (rp, norms, col) ----------
__global__ __launch_bounds__(1024) void k_build(
    const u32* __restrict__ pairs, const int* __restrict__ bbase,
    const int* __restrict__ dego,
    int* __restrict__ rp, int* __restrict__ col,
    float* __restrict__ nin, float* __restrict__ nout,
    int n, int nbuck, int total) {
  __shared__ int cnt[BNODES];
  __shared__ int off_[BNODES];
  __shared__ int cur[BNODES];
  int tid = threadIdx.x;            // 0..1023
  int b = blockIdx.x;
  int base = bbase[b], end = bbase[b + 1];
  int node0 = b << SHIFT;
  cnt[tid] = 0;
  __syncthreads();
  for (int t = base + tid; t < end; t += 1024)
    atomicAdd(&cnt[(int)(pairs[t] >> 22)], 1);
  __syncthreads();
  int c = cnt[tid];
  off_[tid] = c;
  __syncthreads();
  for (int off = 1; off < BNODES; off <<= 1) {
    int add = (tid >= off) ? off_[tid - off] : 0;
    __syncthreads();
    off_[tid] += add;
    __syncthreads();
  }
  int ex = off_[tid] - c;
  int node = node0 + tid;
  if (node < n) {
    rp[node] = base + ex;
    nin[node] = rsqrtf((float)c);              // in-degree incl self-loop
    nout[node] = rsqrtf((float)(dego[node] + 1));
  }
  if (b == nbuck - 1 && tid == 0) rp[n] = total;
  cur[tid] = ex;
  __syncthreads();
  for (int t = base + tid; t < end; t += 1024) {
    u32 pr = pairs[t];
    int p = atomicAdd(&cur[(int)(pr >> 22)], 1);
    col[base + p] = (int)(pr & 0x3FFFFFu);
  }
}

// ---------- pre-scale x by norm_out and convert to bf16 ----------
__global__ __launch_bounds__(256) void k_prescale(
    const float* __restrict__ x, const float* __restrict__ nout,
    u32* __restrict__ xs, int n) {
  int tot = n * 64;   // float2 elements
  const float2* xv = (const float2*)x;
  for (int idx = blockIdx.x * blockDim.x + threadIdx.x; idx < tot;
       idx += gridDim.x * blockDim.x) {
    int row = idx >> 6;
    float w = nout[row];
    float2 v = xv[idx];
    xs[idx] = (u32)f2bf(v.x * w) | ((u32)f2bf(v.y * w) << 16);
  }
}

// ---------- W -> fragment-ordered split-bf16 (hi/lo planes) ----------
__global__ void k_prepw(const float* __restrict__ W, u32* __restrict__ wfhi,
                        u32* __restrict__ wflo) {
  int i = blockIdx.x * 256 + threadIdx.x;   // 8192 u32 per plane
  if (i >= 8192) return;
  int m = i & 3, l = (i >> 2) & 63, f = i >> 8;
  int kt = f & 3, nt = f >> 2;
  int k0 = kt * 32 + ((l >> 4) << 3) + 2 * m;
  int c = nt * 16 + (l & 15);
  float w0 = W[k0 * FD + c], w1 = W[(k0 + 1) * FD + c];
  u16 h0 = f2bf(w0), h1 = f2bf(w1);
  u16 l0 = f2bf(w0 - bf2f(h0)), l1 = f2bf(w1 - bf2f(h1));
  wfhi[i] = (u32)h0 | ((u32)h1 << 16);
  wflo[i] = (u32)l0 | ((u32)l1 << 16);
}

// ---------- aggregation: one wave per dst row, bf16 in, split-bf16 out ----------
__global__ __launch_bounds__(256) void k_agg(
    const u32* __restrict__ hs, const int* __restrict__ rp,
    const int* __restrict__ col, const float* __restrict__ nin,
    u32* __restrict__ ahi, u32* __restrict__ alo, int n) {
  int wid = (blockIdx.x * 256 + threadIdx.x) >> 6;
  int lane = threadIdx.x & 63;
  if (wid >= n) return;
  int e0 = rp[wid], e1 = rp[wid + 1];   // e1 > e0 (self-loop)
  float ax[4] = {0.f, 0.f, 0.f, 0.f};
  float ay[4] = {0.f, 0.f, 0.f, 0.f};
  for (int t = e0; t < e1; t += 8) {
    int s[8]; u32 u[8];
    #pragma unroll
    for (int i = 0; i < 8; ++i) {
      int tt = (t + i < e1) ? (t + i) : (e1 - 1);   // wave-uniform clamp
      s[i] = col[tt];
    }
    #pragma unroll
    for (int i = 0; i < 8; ++i) u[i] = hs[s[i] * 64 + lane];
    #pragma unroll
    for (int i = 0; i < 8; ++i) {
      if (t + i < e1) {                              // wave-uniform predicate
        ax[i & 3] += __uint_as_float(u[i] << 16);
        ay[i & 3] += __uint_as_float(u[i] & 0xFFFF0000u);
      }
    }
  }
  float wi = nin[wid];
  float vx = (ax[0] + ax[1] + ax[2] + ax[3]) * wi;
  float vy = (ay[0] + ay[1] + ay[2] + ay[3]) * wi;
  u16 hx = f2bf(vx), hy = f2bf(vy);
  u16 lx = f2bf(vx - bf2f(hx)), ly = f2bf(vy - bf2f(hy));
  int idx = wid * 64 + (lane ^ ((wid & 7) << 2));   // 16B-chunk XOR swizzle
  ahi[idx] = (u32)hx | ((u32)hy << 16);
  alo[idx] = (u32)lx | ((u32)ly << 16);
}

// ---------- MFMA GEMM: out[64xFD tile] = (Ahi+Alo) @ (Whi+Wlo) + bias ----------
__global__ __launch_bounds__(256) void k_gemm(
    const u32* __restrict__ ahi, const u32* __restrict__ alo,
    const u32* __restrict__ wfhi, const u32* __restrict__ wflo,
    const float* __restrict__ bias, const float* __restrict__ nout,
    float* __restrict__ fout, u16* __restrict__ hsout, int n, int mode) {
  __shared__ u32 Ah[4096];   // 64 rows x 256B (swizzled), 16 KB
  __shared__ u32 Al[4096];
  int tid = threadIdx.x;
  int lane = tid & 63;
  int mt = tid >> 6;
  int r0 = blockIdx.x * 64;

  const u32x4* gh = (const u32x4*)(ahi + (size_t)r0 * 64);
  const u32x4* gl = (const u32x4*)(alo + (size_t)r0 * 64);
  u32x4* sh_ = (u32x4*)Ah;
  u32x4* sl_ = (u32x4*)Al;
  #pragma unroll
  for (int t = 0; t < 4; ++t) {
    sh_[t * 256 + tid] = gh[t * 256 + tid];
    sl_[t * 256 + tid] = gl[t * 256 + tid];
  }
  __syncthreads();

  short8 afh[4], afl[4];
  int arow = mt * 16 + (lane & 15);
  #pragma unroll
  for (int kt = 0; kt < 4; ++kt) {
    int boff = arow * 256 + ((kt * 64 + (lane >> 4) * 16) ^ ((arow & 7) << 4));
    afh[kt] = *(const short8*)((const char*)Ah + boff);
    afl[kt] = *(const short8*)((const char*)Al + boff);
  }

  for (int nt = 0; nt < 8; ++nt) {
    f32x4 acc = {0.f, 0.f, 0.f, 0.f};
    #pragma unroll
    for (int kt = 0; kt < 4; ++kt) {
      int f = nt * 4 + kt;
      short8 wh = *(const short8*)(wfhi + (size_t)(f * 64 + lane) * 4);
      short8 wl = *(const short8*)(wflo + (size_t)(f * 64 + lane) * 4);
      acc = __builtin_amdgcn_mfma_f32_16x16x32_bf16(afh[kt], wh, acc, 0, 0, 0);
      acc = __builtin_amdgcn_mfma_f32_16x16x32_bf16(afh[kt], wl, acc, 0, 0, 0);
      acc = __builtin_amdgcn_mfma_f32_16x16x32_bf16(afl[kt], wh, acc, 0, 0, 0);
    }
    int c = nt * 16 + (lane & 15);
    float bv = bias[c];
    int rbase = r0 + mt * 16 + (lane >> 4) * 4;   // C/D: col=lane&15, row=(lane>>4)*4+j
    if (mode == 0) {
      #pragma unroll
      for (int j = 0; j < 4; ++j) {
        int row = rbase + j;
        if (row < n) fout[(size_t)row * FD + c] = acc[j] + bv;
      }
    } else {
      #pragma unroll
      for (int j = 0; j < 4; ++j) {
        int row = rbase + j;
        if (row < n) hsout[(size_t)row * FD + c] = f2bf((acc[j] + bv) * nout[row]);
      }
    }
  }
}

// ---------------- launch ----------------
extern "C" void kernel_launch(void* const* d_in, const int* in_sizes, int n_in,
                              void* d_out, int out_size, void* d_ws, size_t ws_size,
                              hipStream_t stream) {
  const float* x  = (const float*)d_in[0];
  const int* src  = (const int*)d_in[1];
  const int* dst  = (const int*)d_in[2];
  const float* W1 = (const float*)d_in[3];
  const float* b1 = (const float*)d_in[4];
  const float* W2 = (const float*)d_in[5];
  const float* b2 = (const float*)d_in[6];
  float* out = (float*)d_out;

  int n = in_sizes[0] / FD;      // 100000
  int e = in_sizes[1];           // 1600000
  int total = e + n;
  int nbuck = (n + BNODES - 1) >> SHIFT;   // 98

  char* ws = (char*)d_ws;
  size_t off = 0;
  auto alloc = [&](size_t bytes) -> void* {
    void* p = ws + off;
    off += (bytes + 255) / 256 * 256;
    return p;
  };
  // shared region: pairs (build) -> xs (prescale/agg1) -> h1s (gemm1/agg2)
  u32* shared_ = (u32*)alloc((size_t)n * 64 * 4);    // 25.6 MB
  u32* pairs = shared_;
  u32* xs    = shared_;
  u16* h1s   = (u16*)shared_;
  u32* ahi   = (u32*)alloc((size_t)(n + 64) * 64 * 4);  // 25.6 MB
  u32* alo   = (u32*)alloc((size_t)(n + 64) * 64 * 4);  // 25.6 MB
  int* col   = (int*)alloc((size_t)total * 4);          // 6.8 MB
  int* rp    = (int*)alloc((size_t)(n + 1) * 4);
  float* nin  = (float*)alloc((size_t)n * 4);
  float* nout = (float*)alloc((size_t)n * 4);
  int* dego   = (int*)alloc((size_t)n * 4);
  int* bcnt   = (int*)alloc(NBK * 4);
  int* bbase  = (int*)alloc((NBK + 1) * 4);
  int* bcur   = (int*)alloc(NBK * 4);
  u32* wf1hi  = (u32*)alloc(8192 * 4);
  u32* wf1lo  = (u32*)alloc(8192 * 4);
  u32* wf2hi  = (u32*)alloc(8192 * 4);
  u32* wf2lo  = (u32*)alloc(8192 * 4);

  hipMemsetAsync(dego, 0, (size_t)n * 4, stream);
  hipMemsetAsync(bcnt, 0, (size_t)NBK * 4, stream);

  k_hist<<<256, 512, 0, stream>>>(dst, bcnt, e, n, nbuck);
  k_bscan<<<1, NBK, 0, stream>>>(bcnt, bbase, bcur, nbuck, total);
  k_scatter<<<(total + CHUNK - 1) / CHUNK, ST, 0, stream>>>(
      src, dst, bcur, dego, pairs, e, n, nbuck);
  k_build<<<nbuck, 1024, 0, stream>>>(pairs, bbase, dego, rp, col, nin, nout,
                                      n, nbuck, total);
  k_prepw<<<32, 256, 0, stream>>>(W1, wf1hi, wf1lo);
  k_prepw<<<32, 256, 0, stream>>>(W2, wf2hi, wf2lo);
  k_prescale<<<2048, 256, 0, stream>>>(x, nout, xs, n);

  int agrid = (n + 3) / 4;       // 1 wave per row
  int ggrid = (n + 63) / 64;
  // layer 1
  k_agg<<<agrid, 256, 0, stream>>>(xs, rp, col, nin, ahi, alo, n);
  k_gemm<<<ggrid, 256, 0, stream>>>(ahi, alo, wf1hi, wf1lo, b1, nout,
                                    nullptr, h1s, n, 1);
  // layer 2
  k_agg<<<agrid, 256, 0, stream>>>((const u32*)h1s, rp, col, nin, ahi, alo, n);
  k_gemm<<<ggrid, 256, 0, stream>>>(ahi, alo, wf2hi, wf2lo, b2, nout,
                                    out, nullptr, n, 0);
}

// Round 6
// 347.861 us; speedup vs baseline: 1.8392x; 1.0103x over previous
//
#include <hip/hip_runtime.h>

#define FD 128
#define SHIFT 10         // nodes per bucket = 1024
#define BNODES 1024
#define NBK 128          // padded bucket-array size (98 used)
#define CHUNK 4096       // edges per scatter block
#define ST 512           // scatter block threads

typedef unsigned int u32;
typedef unsigned short u16;
typedef __attribute__((ext_vector_type(8))) short short8;   // 8 bf16 (4 VGPR)
typedef __attribute__((ext_vector_type(4))) float f32x4;
typedef __attribute__((ext_vector_type(4))) u32 u32x4;

__device__ inline u16 f2bf(float f) {            // fp32 -> bf16 RNE
  u32 u = __float_as_uint(f);
  u += 0x7fffu + ((u >> 16) & 1u);
  return (u16)(u >> 16);
}
__device__ inline float bf2f(u16 h) { return __uint_as_float((u32)h << 16); }

// ---------- pass 0: bucket histogram over dst (incl. self-loops) ----------
__global__ __launch_bounds__(512) void k_hist(const int* __restrict__ dst,
                                              int* __restrict__ bcnt,
                                              int e, int n, int nbuck) {
  __shared__ int sh[NBK];
  int tid = threadIdx.x;
  if (tid < NBK) sh[tid] = 0;
  __syncthreads();
  int total = e + n;
  for (int t = blockIdx.x * blockDim.x + tid; t < total; t += gridDim.x * blockDim.x) {
    int d = (t < e) ? dst[t] : (t - e);
    atomicAdd(&sh[d >> SHIFT], 1);
  }
  __syncthreads();
  if (tid < nbuck && sh[tid]) atomicAdd(&bcnt[tid], sh[tid]);
}

// ---------- pass 1: scan buckets ----------
__global__ __launch_bounds__(NBK) void k_bscan(const int* __restrict__ bcnt,
                                               int* __restrict__ bbase,
                                               int* __restrict__ bcur,
                                               int nbuck, int total) {
  __shared__ int sh[NBK];
  int tid = threadIdx.x;
  int v = (tid < nbuck) ? bcnt[tid] : 0;
  sh[tid] = v;
  __syncthreads();
  for (int off = 1; off < NBK; off <<= 1) {
    int add = (tid >= off) ? sh[tid - off] : 0;
    __syncthreads();
    sh[tid] += add;
    __syncthreads();
  }
  if (tid < nbuck) { int ex = sh[tid] - v; bbase[tid] = ex; bcur[tid] = ex; }
  if (tid == 0) bbase[nbuck] = total;
}

// ---------- pass 2: locality-aware scatter of packed (ldst,src) by bucket ----------
// pack: local_dst(10b) << 22 | src(22b)
__global__ __launch_bounds__(ST) void k_scatter(
    const int* __restrict__ src, const int* __restrict__ dst,
    int* __restrict__ bcur, int* __restrict__ dego,
    u32* __restrict__ pairs, int e, int n, int nbuck) {
  __shared__ int hist[NBK];
  __shared__ int incl[NBK];
  __shared__ int excl[NBK];
  __shared__ int gbase[NBK];
  __shared__ int rank[NBK];
  __shared__ u32 stgv[CHUNK];
  __shared__ u16 stgb[CHUNK];
  int tid = threadIdx.x;
  int c0 = blockIdx.x * CHUNK;
  int total = e + n;
  if (tid < NBK) hist[tid] = 0;
  __syncthreads();
  u32 pv_[8]; int b_[8]; bool v_[8];
  #pragma unroll
  for (int i = 0; i < 8; ++i) {
    int t = c0 + i * ST + tid;
    v_[i] = (t < total);
    pv_[i] = 0; b_[i] = 0;
    if (v_[i]) {
      int s, d;
      if (t < e) { s = src[t]; d = dst[t]; atomicAdd(&dego[s], 1); }
      else       { s = t - e;  d = s; }
      pv_[i] = ((u32)(d & (BNODES - 1)) << 22) | (u32)s;
      b_[i] = d >> SHIFT;
      atomicAdd(&hist[b_[i]], 1);
    }
  }
  __syncthreads();
  int h = 0;
  if (tid < NBK) { h = hist[tid]; incl[tid] = h; }
  __syncthreads();
  for (int off = 1; off < NBK; off <<= 1) {
    int add = 0;
    if (tid < NBK && tid >= off) add = incl[tid - off];
    __syncthreads();
    if (tid < NBK) incl[tid] += add;
    __syncthreads();
  }
  if (tid < NBK) {
    int ex = incl[tid] - h;
    excl[tid] = ex;
    rank[tid] = ex;
    if (tid < nbuck && h > 0) gbase[tid] = atomicAdd(&bcur[tid], h);
  }
  __syncthreads();
  #pragma unroll
  for (int i = 0; i < 8; ++i) {
    if (v_[i]) {
      int p = atomicAdd(&rank[b_[i]], 1);
      stgv[p] = pv_[i];
      stgb[p] = (u16)b_[i];
    }
  }
  __syncthreads();
  int V = min(CHUNK, total - c0);
  for (int j = tid; j < V; j += ST) {
    int b = stgb[j];
    pairs[gbase[b] + (j - excl[b])] = stgv[j];   // contiguous runs per bucket
  }
}

// ---------- pass 3: per-bucket CSR finalize (rp, norms, col) ----------
__global__ __launch_bounds__(1024) void k_build(
    const u32* __restrict__ pairs, const int* __restrict__ bbase,
    const int* __restrict__ dego,
    int* __restrict__ rp, int* __restrict__ col,
    float* __restrict__ nin, float* __restrict__ nout,
    int n, int nbuck, int total) {
  __shared__ int cnt[BNODES];
  __shared__ int off_[BNODES];
  __shared__ int cur[BNODES];
  int tid = threadIdx.x;            // 0..1023
  int b = blockIdx.x;
  int base = bbase[b], end = bbase[b + 1];
  int node0 = b << SHIFT;
  cnt[tid] = 0;
  __syncthreads();
  for (int t = base + tid; t < end; t += 1024)
    atomicAdd(&cnt[(int)(pairs[t] >> 22)], 1);
  __syncthreads();
  int c = cnt[tid];
  off_[tid] = c;
  __syncthreads();
  for (int off = 1; off < BNODES; off <<= 1) {
    int add = (tid >= off) ? off_[tid - off] : 0;
    __syncthreads();
    off_[tid] += add;
    __syncthreads();
  }
  int ex = off_[tid] - c;
  int node = node0 + tid;
  if (node < n) {
    rp[node] = base + ex;
    nin[node] = rsqrtf((float)c);              // in-degree incl self-loop
    nout[node] = rsqrtf((float)(dego[node] + 1));
  }
  if (b == nbuck - 1 && tid == 0) rp[n] = total;
  cur[tid] = ex;
  __syncthreads();
  for (int t = base + tid; t < end; t += 1024) {
    u32 pr = pairs[t];
    int p = atomicAdd(&cur[(int)(pr >> 22)], 1);
    col[base + p] = (int)(pr & 0x3FFFFFu);
  }
}

// ---------- pre-scale x by norm_out -> bf16; also zero the sentinel row n ----------
__global__ __launch_bounds__(256) void k_prescale(
    const float* __restrict__ x, const float* __restrict__ nout,
    u32* __restrict__ xs, int n) {
  int tot = (n + 1) * 64;   // float2 elements, incl zero row
  const float2* xv = (const float2*)x;
  for (int idx = blockIdx.x * blockDim.x + threadIdx.x; idx < tot;
       idx += gridDim.x * blockDim.x) {
    int row = idx >> 6;
    if (row >= n) { xs[idx] = 0; }
    else {
      float w = nout[row];
      float2 v = xv[idx];
      xs[idx] = (u32)f2bf(v.x * w) | ((u32)f2bf(v.y * w) << 16);
    }
  }
}

// ---------- W -> fragment-ordered split-bf16 (hi/lo planes) ----------
__global__ void k_prepw(const float* __restrict__ W, u32* __restrict__ wfhi,
                        u32* __restrict__ wflo) {
  int i = blockIdx.x * 256 + threadIdx.x;   // 8192 u32 per plane
  if (i >= 8192) return;
  int m = i & 3, l = (i >> 2) & 63, f = i >> 8;
  int kt = f & 3, nt = f >> 2;
  int k0 = kt * 32 + ((l >> 4) << 3) + 2 * m;
  int c = nt * 16 + (l & 15);
  float w0 = W[k0 * FD + c], w1 = W[(k0 + 1) * FD + c];
  u16 h0 = f2bf(w0), h1 = f2bf(w1);
  u16 l0 = f2bf(w0 - bf2f(h0)), l1 = f2bf(w1 - bf2f(h1));
  wfhi[i] = (u32)h0 | ((u32)h1 << 16);
  wflo[i] = (u32)l0 | ((u32)l1 << 16);
}

// ---------- aggregation: one wave per dst row; dwordx4 gathers (4 edges/instr) ----------
// lane group g=lane>>4 handles edge t+h*4+g; lane&15 picks the 16B chunk.
// invalid slots read the zero row (index n). Final shfl reduce across groups.
__global__ __launch_bounds__(256) void k_agg(
    const u32* __restrict__ hs, const int* __restrict__ rp,
    const int* __restrict__ col, const float* __restrict__ nin,
    u32* __restrict__ ahi, u32* __restrict__ alo, int n) {
  int wid = (blockIdx.x * 256 + threadIdx.x) >> 6;
  int lane = threadIdx.x & 63;
  if (wid >= n) return;
  int e0 = rp[wid], e1 = rp[wid + 1];   // e1 > e0 (self-loop)
  int g = lane >> 4;
  int ch = lane & 15;
  float acc[8] = {0.f, 0.f, 0.f, 0.f, 0.f, 0.f, 0.f, 0.f};
  const u32x4* hv = (const u32x4*)hs;   // 16 chunks per row
  for (int t = e0 & ~7; t < e1; t += 8) {
    int4 c0 = *(const int4*)(col + t);       // 32B-aligned broadcast
    int4 c1 = *(const int4*)(col + t + 4);
    #pragma unroll
    for (int h = 0; h < 2; ++h) {
      int idx = t + h * 4 + g;
      int4 cc = h ? c1 : c0;
      int s = (g & 2) ? ((g & 1) ? cc.w : cc.z) : ((g & 1) ? cc.y : cc.x);
      s = (idx >= e0 && idx < e1) ? s : n;   // zero row for pad slots
      u32x4 v = hv[(size_t)s * 16 + ch];
      #pragma unroll
      for (int j = 0; j < 4; ++j) {
        u32 u = v[j];
        acc[2 * j]     += __uint_as_float(u << 16);
        acc[2 * j + 1] += __uint_as_float(u & 0xFFFF0000u);
      }
    }
  }
  // reduce across the 4 lane groups (feature chunks identical across groups)
  #pragma unroll
  for (int j = 0; j < 8; ++j) {
    acc[j] += __shfl_xor(acc[j], 16, 64);
    acc[j] += __shfl_xor(acc[j], 32, 64);
  }
  float wi = nin[wid];
  u32 hi[4], lo[4];
  #pragma unroll
  for (int j = 0; j < 4; ++j) {
    float v0 = acc[2 * j] * wi, v1 = acc[2 * j + 1] * wi;
    u16 h0 = f2bf(v0), h1 = f2bf(v1);
    hi[j] = (u32)h0 | ((u32)h1 << 16);
    lo[j] = (u32)f2bf(v0 - bf2f(h0)) | ((u32)f2bf(v1 - bf2f(h1)) << 16);
  }
  int sch = ch ^ (wid & 7);                 // 16B-chunk XOR swizzle
  size_t base = (size_t)wid * 64 + sch * 4;
  u32x4 hq = {hi[0], hi[1], hi[2], hi[3]};
  u32x4 lq = {lo[0], lo[1], lo[2], lo[3]};
  if (g == 0)      *(u32x4*)(ahi + base) = hq;
  else if (g == 1) *(u32x4*)(alo + base) = lq;
}

// ---------- MFMA GEMM: out[64xFD tile] = (Ahi+Alo) @ (Whi+Wlo) + bias ----------
__global__ __launch_bounds__(256) void k_gemm(
    const u32* __restrict__ ahi, const u32* __restrict__ alo,
    const u32* __restrict__ wfhi, const u32* __restrict__ wflo,
    const float* __restrict__ bias, const float* __restrict__ nout,
    float* __restrict__ fout, u16* __restrict__ hsout, int n, int mode) {
  __shared__ u32 Ah[4096];   // 64 rows x 256B (swizzled), 16 KB
  __shared__ u32 Al[4096];
  int tid = threadIdx.x;
  int lane = tid & 63;
  int mt = tid >> 6;
  int r0 = blockIdx.x * 64;

  const u32x4* gh = (const u32x4*)(ahi + (size_t)r0 * 64);
  const u32x4* gl = (const u32x4*)(alo + (size_t)r0 * 64);
  u32x4* sh_ = (u32x4*)Ah;
  u32x4* sl_ = (u32x4*)Al;
  #pragma unroll
  for (int t = 0; t < 4; ++t) {
    sh_[t * 256 + tid] = gh[t * 256 + tid];
    sl_[t * 256 + tid] = gl[t * 256 + tid];
  }
  __syncthreads();

  short8 afh[4], afl[4];
  int arow = mt * 16 + (lane & 15);
  #pragma unroll
  for (int kt = 0; kt < 4; ++kt) {
    int boff = arow * 256 + ((kt * 64 + (lane >> 4) * 16) ^ ((arow & 7) << 4));
    afh[kt] = *(const short8*)((const char*)Ah + boff);
    afl[kt] = *(const short8*)((const char*)Al + boff);
  }

  for (int nt = 0; nt < 8; ++nt) {
    f32x4 acc = {0.f, 0.f, 0.f, 0.f};
    #pragma unroll
    for (int kt = 0; kt < 4; ++kt) {
      int f = nt * 4 + kt;
      short8 wh = *(const short8*)(wfhi + (size_t)(f * 64 + lane) * 4);
      short8 wl = *(const short8*)(wflo + (size_t)(f * 64 + lane) * 4);
      acc = __builtin_amdgcn_mfma_f32_16x16x32_bf16(afh[kt], wh, acc, 0, 0, 0);
      acc = __builtin_amdgcn_mfma_f32_16x16x32_bf16(afh[kt], wl, acc, 0, 0, 0);
      acc = __builtin_amdgcn_mfma_f32_16x16x32_bf16(afl[kt], wh, acc, 0, 0, 0);
    }
    int c = nt * 16 + (lane & 15);
    float bv = bias[c];
    int rbase = r0 + mt * 16 + (lane >> 4) * 4;   // C/D: col=lane&15, row=(lane>>4)*4+j
    if (mode == 0) {
      #pragma unroll
      for (int j = 0; j < 4; ++j) {
        int row = rbase + j;
        if (row < n) fout[(size_t)row * FD + c] = acc[j] + bv;
      }
    } else {
      #pragma unroll
      for (int j = 0; j < 4; ++j) {
        int row = rbase + j;
        if (row < n) hsout[(size_t)row * FD + c] = f2bf((acc[j] + bv) * nout[row]);
      }
    }
  }
}

// ---------------- launch ----------------
extern "C" void kernel_launch(void* const* d_in, const int* in_sizes, int n_in,
                              void* d_out, int out_size, void* d_ws, size_t ws_size,
                              hipStream_t stream) {
  const float* x  = (const float*)d_in[0];
  const int* src  = (const int*)d_in[1];
  const int* dst  = (const int*)d_in[2];
  const float* W1 = (const float*)d_in[3];
  const float* b1 = (const float*)d_in[4];
  const float* W2 = (const float*)d_in[5];
  const float* b2 = (const float*)d_in[6];
  float* out = (float*)d_out;

  int n = in_sizes[0] / FD;      // 100000
  int e = in_sizes[1];           // 1600000
  int total = e + n;
  int nbuck = (n + BNODES - 1) >> SHIFT;   // 98

  char* ws = (char*)d_ws;
  size_t off = 0;
  auto alloc = [&](size_t bytes) -> void* {
    void* p = ws + off;
    off += (bytes + 255) / 256 * 256;
    return p;
  };
  // shared region: pairs (build) -> xs (prescale/agg1) -> h1s (gemm1/agg2)
  // row n is the zero sentinel row (zeroed by prescale; gemm writes only rows<n)
  u32* shared_ = (u32*)alloc((size_t)(n + 16) * 64 * 4);   // 25.6 MB
  u32* pairs = shared_;
  u32* xs    = shared_;
  u16* h1s   = (u16*)shared_;
  u32* ahi   = (u32*)alloc((size_t)(n + 64) * 64 * 4);  // 25.6 MB
  u32* alo   = (u32*)alloc((size_t)(n + 64) * 64 * 4);  // 25.6 MB
  int* col   = (int*)alloc((size_t)total * 4 + 64);     // 6.8 MB (+tail slack)
  int* rp    = (int*)alloc((size_t)(n + 1) * 4);
  float* nin  = (float*)alloc((size_t)n * 4);
  float* nout = (float*)alloc((size_t)n * 4);
  int* dego   = (int*)alloc((size_t)n * 4);
  int* bcnt   = (int*)alloc(NBK * 4);
  int* bbase  = (int*)alloc((NBK + 1) * 4);
  int* bcur   = (int*)alloc(NBK * 4);
  u32* wf1hi  = (u32*)alloc(8192 * 4);
  u32* wf1lo  = (u32*)alloc(8192 * 4);
  u32* wf2hi  = (u32*)alloc(8192 * 4);
  u32* wf2lo  = (u32*)alloc(8192 * 4);

  hipMemsetAsync(dego, 0, (size_t)n * 4, stream);
  hipMemsetAsync(bcnt, 0, (size_t)NBK * 4, stream);

  k_hist<<<256, 512, 0, stream>>>(dst, bcnt, e, n, nbuck);
  k_bscan<<<1, NBK, 0, stream>>>(bcnt, bbase, bcur, nbuck, total);
  k_scatter<<<(total + CHUNK - 1) / CHUNK, ST, 0, stream>>>(
      src, dst, bcur, dego, pairs, e, n, nbuck);
  k_build<<<nbuck, 1024, 0, stream>>>(pairs, bbase, dego, rp, col, nin, nout,
                                      n, nbuck, total);
  k_prepw<<<32, 256, 0, stream>>>(W1, wf1hi, wf1lo);
  k_prepw<<<32, 256, 0, stream>>>(W2, wf2hi, wf2lo);
  k_prescale<<<2048, 256, 0, stream>>>(x, nout, xs, n);

  int agrid = (n + 3) / 4;       // 1 wave per row
  int ggrid = (n + 63) / 64;
  // layer 1
  k_agg<<<agrid, 256, 0, stream>>>(xs, rp, col, nin, ahi, alo, n);
  k_gemm<<<ggrid, 256, 0, stream>>>(ahi, alo, wf1hi, wf1lo, b1, nout,
                                    nullptr, h1s, n, 1);
  // layer 2
  k_agg<<<agrid, 256, 0, stream>>>((const u32*)h1s, rp, col, nin, ahi, alo, n);
  k_gemm<<<ggrid, 256, 0, stream>>>(ahi, alo, wf2hi, wf2lo, b2, nout,
                                    out, nullptr, n, 0);
}

// Round 7
// 295.574 us; speedup vs baseline: 2.1645x; 1.1769x over previous
//
#include <hip/hip_runtime.h>

#define FD 128
#define SHIFT 10         // nodes per bucket = 1024
#define BNODES 1024
#define NBK 128          // padded bucket-array size (98 used)
#define CHUNK 4096       // edges per scatter block
#define ST 512           // scatter block threads

typedef unsigned int u32;
typedef unsigned short u16;
typedef __attribute__((ext_vector_type(8))) short short8;   // 8 bf16 (4 VGPR)
typedef __attribute__((ext_vector_type(4))) float f32x4;
typedef __attribute__((ext_vector_type(4))) u32 u32x4;

__device__ inline u16 f2bf(float f) {            // fp32 -> bf16 RNE
  u32 u = __float_as_uint(f);
  u += 0x7fffu + ((u >> 16) & 1u);
  return (u16)(u >> 16);
}
__device__ inline float bf2f(u16 h) { return __uint_as_float((u32)h << 16); }

// ---------- pass 0: bucket histogram over dst (incl. self-loops) ----------
__global__ __launch_bounds__(512) void k_hist(const int* __restrict__ dst,
                                              int* __restrict__ bcnt,
                                              int e, int n, int nbuck) {
  __shared__ int sh[NBK];
  int tid = threadIdx.x;
  if (tid < NBK) sh[tid] = 0;
  __syncthreads();
  int total = e + n;
  for (int t = blockIdx.x * blockDim.x + tid; t < total; t += gridDim.x * blockDim.x) {
    int d = (t < e) ? dst[t] : (t - e);
    atomicAdd(&sh[d >> SHIFT], 1);
  }
  __syncthreads();
  if (tid < nbuck && sh[tid]) atomicAdd(&bcnt[tid], sh[tid]);
}

// ---------- pass 1: scan buckets ----------
__global__ __launch_bounds__(NBK) void k_bscan(const int* __restrict__ bcnt,
                                               int* __restrict__ bbase,
                                               int* __restrict__ bcur,
                                               int nbuck, int total) {
  __shared__ int sh[NBK];
  int tid = threadIdx.x;
  int v = (tid < nbuck) ? bcnt[tid] : 0;
  sh[tid] = v;
  __syncthreads();
  for (int off = 1; off < NBK; off <<= 1) {
    int add = (tid >= off) ? sh[tid - off] : 0;
    __syncthreads();
    sh[tid] += add;
    __syncthreads();
  }
  if (tid < nbuck) { int ex = sh[tid] - v; bbase[tid] = ex; bcur[tid] = ex; }
  if (tid == 0) bbase[nbuck] = total;
}

// ---------- pass 2: locality-aware scatter of packed (ldst,src) by bucket ----------
// pack: local_dst(10b) << 22 | src(22b)
__global__ __launch_bounds__(ST) void k_scatter(
    const int* __restrict__ src, const int* __restrict__ dst,
    int* __restrict__ bcur, int* __restrict__ dego,
    u32* __restrict__ pairs, int e, int n, int nbuck) {
  __shared__ int hist[NBK];
  __shared__ int incl[NBK];
  __shared__ int excl[NBK];
  __shared__ int gbase[NBK];
  __shared__ int rank[NBK];
  __shared__ u32 stgv[CHUNK];
  __shared__ u16 stgb[CHUNK];
  int tid = threadIdx.x;
  int c0 = blockIdx.x * CHUNK;
  int total = e + n;
  if (tid < NBK) hist[tid] = 0;
  __syncthreads();
  u32 pv_[8]; int b_[8]; bool v_[8];
  #pragma unroll
  for (int i = 0; i < 8; ++i) {
    int t = c0 + i * ST + tid;
    v_[i] = (t < total);
    pv_[i] = 0; b_[i] = 0;
    if (v_[i]) {
      int s, d;
      if (t < e) { s = src[t]; d = dst[t]; atomicAdd(&dego[s], 1); }
      else       { s = t - e;  d = s; }
      pv_[i] = ((u32)(d & (BNODES - 1)) << 22) | (u32)s;
      b_[i] = d >> SHIFT;
      atomicAdd(&hist[b_[i]], 1);
    }
  }
  __syncthreads();
  int h = 0;
  if (tid < NBK) { h = hist[tid]; incl[tid] = h; }
  __syncthreads();
  for (int off = 1; off < NBK; off <<= 1) {
    int add = 0;
    if (tid < NBK && tid >= off) add = incl[tid - off];
    __syncthreads();
    if (tid < NBK) incl[tid] += add;
    __syncthreads();
  }
  if (tid < NBK) {
    int ex = incl[tid] - h;
    excl[tid] = ex;
    rank[tid] = ex;
    if (tid < nbuck && h > 0) gbase[tid] = atomicAdd(&bcur[tid], h);
  }
  __syncthreads();
  #pragma unroll
  for (int i = 0; i < 8; ++i) {
    if (v_[i]) {
      int p = atomicAdd(&rank[b_[i]], 1);
      stgv[p] = pv_[i];
      stgb[p] = (u16)b_[i];
    }
  }
  __syncthreads();
  int V = min(CHUNK, total - c0);
  for (int j = tid; j < V; j += ST) {
    int b = stgb[j];
    pairs[gbase[b] + (j - excl[b])] = stgv[j];   // contiguous runs per bucket
  }
}

// ---------- pass 3: per-bucket CSR finalize (rp, norms, col) ----------
__global__ __launch_bounds__(1024) void k_build(
    const u32* __restrict__ pairs, const int* __restrict__ bbase,
    const int* __restrict__ dego,
    int* __restrict__ rp, int* __restrict__ col,
    float* __restrict__ nin, float* __restrict__ nout,
    int n, int nbuck, int total) {
  __shared__ int cnt[BNODES];
  __shared__ int off_[BNODES];
  __shared__ int cur[BNODES];
  int tid = threadIdx.x;            // 0..1023
  int b = blockIdx.x;
  int base = bbase[b], end = bbase[b + 1];
  int node0 = b << SHIFT;
  cnt[tid] = 0;
  __syncthreads();
  for (int t = base + tid; t < end; t += 1024)
    atomicAdd(&cnt[(int)(pairs[t] >> 22)], 1);
  __syncthreads();
  int c = cnt[tid];
  off_[tid] = c;
  __syncthreads();
  for (int off = 1; off < BNODES; off <<= 1) {
    int add = (tid >= off) ? off_[tid - off] : 0;
    __syncthreads();
    off_[tid] += add;
    __syncthreads();
  }
  int ex = off_[tid] - c;
  int node = node0 + tid;
  if (node < n) {
    rp[node] = base + ex;
    nin[node] = rsqrtf((float)c);              // in-degree incl self-loop
    nout[node] = rsqrtf((float)(dego[node] + 1));
  }
  if (b == nbuck - 1 && tid == 0) rp[n] = total;
  cur[tid] = ex;
  __syncthreads();
  for (int t = base + tid; t < end; t += 1024) {
    u32 pr = pairs[t];
    int p = atomicAdd(&cur[(int)(pr >> 22)], 1);
    col[base + p] = (int)(pr & 0x3FFFFFu);
  }
}

// ---------- pre-scale x by norm_out -> bf16; also zero the sentinel row n ----------
__global__ __launch_bounds__(256) void k_prescale(
    const float* __restrict__ x, const float* __restrict__ nout,
    u32* __restrict__ xs, int n) {
  int tot = (n + 1) * 64;   // float2 elements, incl zero row
  const float2* xv = (const float2*)x;
  for (int idx = blockIdx.x * blockDim.x + threadIdx.x; idx < tot;
       idx += gridDim.x * blockDim.x) {
    int row = idx >> 6;
    if (row >= n) { xs[idx] = 0; }
    else {
      float w = nout[row];
      float2 v = xv[idx];
      xs[idx] = (u32)f2bf(v.x * w) | ((u32)f2bf(v.y * w) << 16);
    }
  }
}

// ---------- W -> fragment-ordered split-bf16 (hi/lo planes); both W1 and W2 ----------
__global__ void k_prepw(const float* __restrict__ W1, u32* __restrict__ wf1hi,
                        u32* __restrict__ wf1lo,
                        const float* __restrict__ W2, u32* __restrict__ wf2hi,
                        u32* __restrict__ wf2lo) {
  int gi = blockIdx.x * 256 + threadIdx.x;   // 2 x 8192
  int i = gi & 8191;
  const float* W = (gi < 8192) ? W1 : W2;
  u32* wfhi = (gi < 8192) ? wf1hi : wf2hi;
  u32* wflo = (gi < 8192) ? wf1lo : wf2lo;
  int m = i & 3, l = (i >> 2) & 63, f = i >> 8;
  int kt = f & 3, nt = f >> 2;
  int k0 = kt * 32 + ((l >> 4) << 3) + 2 * m;
  int c = nt * 16 + (l & 15);
  float w0 = W[k0 * FD + c], w1 = W[(k0 + 1) * FD + c];
  u16 h0 = f2bf(w0), h1 = f2bf(w1);
  u16 l0 = f2bf(w0 - bf2f(h0)), l1 = f2bf(w1 - bf2f(h1));
  wfhi[i] = (u32)h0 | ((u32)h1 << 16);
  wflo[i] = (u32)l0 | ((u32)l1 << 16);
}

// ---------- aggregation v2: 4 rows per wave, one per 16-lane group ----------
// 8 independent full-row gathers in flight per trip; sentinel row n pads.
// output: bf16 hi plane only, chunk-XOR-swizzled for the GEMM.
__global__ __launch_bounds__(256) void k_agg(
    const u32* __restrict__ hs, const int* __restrict__ rp,
    const int* __restrict__ col, const float* __restrict__ nin,
    u32* __restrict__ ahi, int n) {
  int wv = (blockIdx.x * 256 + threadIdx.x) >> 6;   // global wave id
  int lane = threadIdx.x & 63;
  int g = lane >> 4, ch = lane & 15;
  int r = wv * 4 + g;
  bool valid = (r < n);
  int e0 = 0, e1 = 0;
  if (valid) { e0 = rp[r]; e1 = rp[r + 1]; }   // e1 > e0 (self-loop)
  // wave-max degree over the 4 groups
  int m = e1 - e0;
  m = max(m, __shfl_xor(m, 16, 64));
  m = max(m, __shfl_xor(m, 32, 64));
  int trips = (m + 7) >> 3;
  float acc[8] = {0.f, 0.f, 0.f, 0.f, 0.f, 0.f, 0.f, 0.f};
  const u32x4* hv = (const u32x4*)hs;   // 16 chunks per row
  int em1 = (e1 > 0) ? (e1 - 1) : 0;
  for (int it = 0; it < trips; ++it) {
    int tb = e0 + it * 8;
    u32x4 buf[8];
    #pragma unroll
    for (int u = 0; u < 8; ++u) {
      int idx = tb + u;
      int s = col[min(idx, em1)];          // group-uniform broadcast load
      s = (idx < e1) ? s : n;              // sentinel zero row for pads
      buf[u] = hv[(size_t)s * 16 + ch];
    }
    #pragma unroll
    for (int u = 0; u < 8; ++u)
      #pragma unroll
      for (int j = 0; j < 4; ++j) {
        u32 x = buf[u][j];
        acc[2 * j]     += __uint_as_float(x << 16);
        acc[2 * j + 1] += __uint_as_float(x & 0xFFFF0000u);
      }
  }
  if (!valid) return;
  float wi = nin[r];
  u32 hi[4];
  #pragma unroll
  for (int j = 0; j < 4; ++j) {
    float v0 = acc[2 * j] * wi, v1 = acc[2 * j + 1] * wi;
    hi[j] = (u32)f2bf(v0) | ((u32)f2bf(v1) << 16);
  }
  int sch = ch ^ (r & 7);                 // 16B-chunk XOR swizzle
  u32x4 hq = {hi[0], hi[1], hi[2], hi[3]};
  *(u32x4*)(ahi + (size_t)r * 64 + sch * 4) = hq;
}

// ---------- MFMA GEMM: out[64xFD tile] = Ahi @ (Whi+Wlo) + bias ----------
__global__ __launch_bounds__(256) void k_gemm(
    const u32* __restrict__ ahi,
    const u32* __restrict__ wfhi, const u32* __restrict__ wflo,
    const float* __restrict__ bias, const float* __restrict__ nout,
    float* __restrict__ fout, u16* __restrict__ hsout, int n, int mode) {
  __shared__ u32 Ah[4096];   // 64 rows x 256B (swizzled), 16 KB
  int tid = threadIdx.x;
  int lane = tid & 63;
  int mt = tid >> 6;
  int r0 = blockIdx.x * 64;

  const u32x4* gh = (const u32x4*)(ahi + (size_t)r0 * 64);
  u32x4* sh_ = (u32x4*)Ah;
  #pragma unroll
  for (int t = 0; t < 4; ++t) sh_[t * 256 + tid] = gh[t * 256 + tid];
  __syncthreads();

  short8 afh[4];
  int arow = mt * 16 + (lane & 15);
  #pragma unroll
  for (int kt = 0; kt < 4; ++kt) {
    int boff = arow * 256 + ((kt * 64 + (lane >> 4) * 16) ^ ((arow & 7) << 4));
    afh[kt] = *(const short8*)((const char*)Ah + boff);
  }

  for (int nt = 0; nt < 8; ++nt) {
    f32x4 acc = {0.f, 0.f, 0.f, 0.f};
    #pragma unroll
    for (int kt = 0; kt < 4; ++kt) {
      int f = nt * 4 + kt;
      short8 wh = *(const short8*)(wfhi + (size_t)(f * 64 + lane) * 4);
      short8 wl = *(const short8*)(wflo + (size_t)(f * 64 + lane) * 4);
      acc = __builtin_amdgcn_mfma_f32_16x16x32_bf16(afh[kt], wh, acc, 0, 0, 0);
      acc = __builtin_amdgcn_mfma_f32_16x16x32_bf16(afh[kt], wl, acc, 0, 0, 0);
    }
    int c = nt * 16 + (lane & 15);
    float bv = bias[c];
    int rbase = r0 + mt * 16 + (lane >> 4) * 4;   // C/D: col=lane&15, row=(lane>>4)*4+j
    if (mode == 0) {
      #pragma unroll
      for (int j = 0; j < 4; ++j) {
        int row = rbase + j;
        if (row < n) fout[(size_t)row * FD + c] = acc[j] + bv;
      }
    } else {
      #pragma unroll
      for (int j = 0; j < 4; ++j) {
        int row = rbase + j;
        if (row < n) hsout[(size_t)row * FD + c] = f2bf((acc[j] + bv) * nout[row]);
      }
    }
  }
}

// ---------------- launch ----------------
extern "C" void kernel_launch(void* const* d_in, const int* in_sizes, int n_in,
                              void* d_out, int out_size, void* d_ws, size_t ws_size,
                              hipStream_t stream) {
  const float* x  = (const float*)d_in[0];
  const int* src  = (const int*)d_in[1];
  const int* dst  = (const int*)d_in[2];
  const float* W1 = (const float*)d_in[3];
  const float* b1 = (const float*)d_in[4];
  const float* W2 = (const float*)d_in[5];
  const float* b2 = (const float*)d_in[6];
  float* out = (float*)d_out;

  int n = in_sizes[0] / FD;      // 100000
  int e = in_sizes[1];           // 1600000
  int total = e + n;
  int nbuck = (n + BNODES - 1) >> SHIFT;   // 98

  char* ws = (char*)d_ws;
  size_t off = 0;
  auto alloc = [&](size_t bytes) -> void* {
    void* p = ws + off;
    off += (bytes + 255) / 256 * 256;
    return p;
  };
  // shared region: pairs (build) -> xs (prescale/agg1) -> h1s (gemm1/agg2)
  // row n is the zero sentinel row (zeroed by prescale; gemm writes only rows<n)
  u32* shared_ = (u32*)alloc((size_t)(n + 16) * 64 * 4);   // 25.6 MB
  u32* pairs = shared_;
  u32* xs    = shared_;
  u16* h1s   = (u16*)shared_;
  u32* ahi   = (u32*)alloc((size_t)(n + 64) * 64 * 4);  // 25.6 MB
  int* col   = (int*)alloc((size_t)total * 4 + 256);    // 6.8 MB (+tail slack)
  int* rp    = (int*)alloc((size_t)(n + 1) * 4);
  float* nin  = (float*)alloc((size_t)n * 4);
  float* nout = (float*)alloc((size_t)n * 4);
  int* dego   = (int*)alloc((size_t)n * 4);
  int* bcnt   = (int*)alloc(NBK * 4);
  int* bbase  = (int*)alloc((NBK + 1) * 4);
  int* bcur   = (int*)alloc(NBK * 4);
  u32* wf1hi  = (u32*)alloc(8192 * 4);
  u32* wf1lo  = (u32*)alloc(8192 * 4);
  u32* wf2hi  = (u32*)alloc(8192 * 4);
  u32* wf2lo  = (u32*)alloc(8192 * 4);

  hipMemsetAsync(dego, 0, (size_t)n * 4, stream);
  hipMemsetAsync(bcnt, 0, (size_t)NBK * 4, stream);

  k_hist<<<256, 512, 0, stream>>>(dst, bcnt, e, n, nbuck);
  k_bscan<<<1, NBK, 0, stream>>>(bcnt, bbase, bcur, nbuck, total);
  k_scatter<<<(total + CHUNK - 1) / CHUNK, ST, 0, stream>>>(
      src, dst, bcur, dego, pairs, e, n, nbuck);
  k_build<<<nbuck, 1024, 0, stream>>>(pairs, bbase, dego, rp, col, nin, nout,
                                      n, nbuck, total);
  k_prepw<<<64, 256, 0, stream>>>(W1, wf1hi, wf1lo, W2, wf2hi, wf2lo);
  k_prescale<<<2048, 256, 0, stream>>>(x, nout, xs, n);

  int agrid = (n + 15) / 16;     // 4 rows/wave, 4 waves/block
  int ggrid = (n + 63) / 64;
  // layer 1
  k_agg<<<agrid, 256, 0, stream>>>(xs, rp, col, nin, ahi, n);
  k_gemm<<<ggrid, 256, 0, stream>>>(ahi, wf1hi, wf1lo, b1, nout,
                                    nullptr, h1s, n, 1);
  // layer 2
  k_agg<<<agrid, 256, 0, stream>>>((const u32*)h1s, rp, col, nin, ahi, n);
  k_gemm<<<ggrid, 256, 0, stream>>>(ahi, wf2hi, wf2lo, b2, nout,
                                    out, nullptr, n, 0);
}

// Round 8
// 251.065 us; speedup vs baseline: 2.5483x; 1.1773x over previous
//
#include <hip/hip_runtime.h>

#define FD 128
#define SHIFT 10         // nodes per bucket = 1024
#define BNODES 1024
#define NBK 128          // padded bucket-array size (98 used)
#define CHUNK 4096       // edges per scatter block
#define ST 512           // scatter block threads

typedef unsigned int u32;
typedef unsigned short u16;
typedef unsigned char u8;
typedef __attribute__((ext_vector_type(8))) short short8;   // 8 bf16 (4 VGPR)
typedef __attribute__((ext_vector_type(4))) float f32x4;
typedef __attribute__((ext_vector_type(4))) u32 u32x4;

__device__ inline u16 f2bf(float f) {            // fp32 -> bf16 RNE
  u32 u = __float_as_uint(f);
  u += 0x7fffu + ((u >> 16) & 1u);
  return (u16)(u >> 16);
}
__device__ inline float bf2f(u16 h) { return __uint_as_float((u32)h << 16); }

// ---------- pass 0: bucket histograms (dst incl self-loops; src real edges) ----------
__global__ __launch_bounds__(512) void k_hist(const int* __restrict__ src,
                                              const int* __restrict__ dst,
                                              int* __restrict__ bcntD,
                                              int* __restrict__ bcntS,
                                              int e, int n, int nbuck) {
  __shared__ int shD[NBK];
  __shared__ int shS[NBK];
  int tid = threadIdx.x;
  if (tid < NBK) { shD[tid] = 0; shS[tid] = 0; }
  __syncthreads();
  int total = e + n;
  for (int t = blockIdx.x * blockDim.x + tid; t < total; t += gridDim.x * blockDim.x) {
    if (t < e) {
      atomicAdd(&shD[dst[t] >> SHIFT], 1);
      atomicAdd(&shS[src[t] >> SHIFT], 1);
    } else {
      atomicAdd(&shD[(t - e) >> SHIFT], 1);
    }
  }
  __syncthreads();
  if (tid < nbuck) {
    if (shD[tid]) atomicAdd(&bcntD[tid], shD[tid]);
    if (shS[tid]) atomicAdd(&bcntS[tid], shS[tid]);
  }
}

// ---------- pass 1: scan both bucket arrays ----------
__global__ __launch_bounds__(NBK) void k_bscan(
    const int* __restrict__ bcntD, const int* __restrict__ bcntS,
    int* __restrict__ bbaseD, int* __restrict__ bcurD,
    int* __restrict__ bbaseS, int* __restrict__ bcurS,
    int nbuck, int totalD, int totalS) {
  __shared__ int shD[NBK];
  __shared__ int shS[NBK];
  int tid = threadIdx.x;
  int vD = (tid < nbuck) ? bcntD[tid] : 0;
  int vS = (tid < nbuck) ? bcntS[tid] : 0;
  shD[tid] = vD; shS[tid] = vS;
  __syncthreads();
  for (int off = 1; off < NBK; off <<= 1) {
    int aD = (tid >= off) ? shD[tid - off] : 0;
    int aS = (tid >= off) ? shS[tid - off] : 0;
    __syncthreads();
    shD[tid] += aD; shS[tid] += aS;
    __syncthreads();
  }
  if (tid < nbuck) {
    int exD = shD[tid] - vD; bbaseD[tid] = exD; bcurD[tid] = exD;
    int exS = shS[tid] - vS; bbaseS[tid] = exS; bcurS[tid] = exS;
  }
  if (tid == 0) { bbaseD[nbuck] = totalD; bbaseS[nbuck] = totalS; }
}

// ---------- pass 2: dual locality-aware scatter (dst-keyed u32, src-keyed u16) ----------
// NO per-node device atomics. pack: local_dst(10b) << 22 | src(22b)
__global__ __launch_bounds__(ST) void k_scatter(
    const int* __restrict__ src, const int* __restrict__ dst,
    int* __restrict__ bcurD, int* __restrict__ bcurS,
    u32* __restrict__ pairs, u16* __restrict__ pairs2,
    int e, int n, int nbuck) {
  __shared__ int histD[NBK], exclD[NBK], gbaseD[NBK], rankD[NBK];
  __shared__ int histS[NBK], exclS[NBK], gbaseS[NBK], rankS[NBK];
  __shared__ u32 stgv[CHUNK];
  __shared__ u8  stgb[CHUNK];
  __shared__ u16 stg2[CHUNK];
  __shared__ u8  stg2b[CHUNK];
  int tid = threadIdx.x;
  int c0 = blockIdx.x * CHUNK;
  int total = e + n;
  if (tid < NBK) { histD[tid] = 0; histS[tid] = 0; }
  __syncthreads();
  u32 pv_[8]; int bD_[8], bS_[8]; bool v_[8], vs_[8];
  #pragma unroll
  for (int i = 0; i < 8; ++i) {
    int t = c0 + i * ST + tid;
    v_[i] = (t < total);
    vs_[i] = (t < e);
    pv_[i] = 0; bD_[i] = 0; bS_[i] = 0;
    if (v_[i]) {
      int s, d;
      if (vs_[i]) { s = src[t]; d = dst[t]; }
      else        { s = t - e;  d = s; }
      pv_[i] = ((u32)(d & (BNODES - 1)) << 22) | (u32)s;
      bD_[i] = d >> SHIFT;
      atomicAdd(&histD[bD_[i]], 1);
      if (vs_[i]) { bS_[i] = s >> SHIFT; atomicAdd(&histS[bS_[i]], 1); }
    }
  }
  __syncthreads();
  int hD = 0, hS = 0;
  if (tid < NBK) { hD = histD[tid]; hS = histS[tid]; }
  __syncthreads();
  for (int off = 1; off < NBK; off <<= 1) {
    int aD = 0, aS = 0;
    if (tid < NBK && tid >= off) { aD = histD[tid - off]; aS = histS[tid - off]; }
    __syncthreads();
    if (tid < NBK) { histD[tid] += aD; histS[tid] += aS; }
    __syncthreads();
  }
  if (tid < NBK) {
    int exD = histD[tid] - hD; exclD[tid] = exD; rankD[tid] = exD;
    int exS = histS[tid] - hS; exclS[tid] = exS; rankS[tid] = exS;
    gbaseD[tid] = (tid < nbuck && hD > 0) ? atomicAdd(&bcurD[tid], hD) : 0;
    gbaseS[tid] = (tid < nbuck && hS > 0) ? atomicAdd(&bcurS[tid], hS) : 0;
  }
  __syncthreads();
  #pragma unroll
  for (int i = 0; i < 8; ++i) {
    if (v_[i]) {
      int p = atomicAdd(&rankD[bD_[i]], 1);
      stgv[p] = pv_[i];
      stgb[p] = (u8)bD_[i];
    }
    if (vs_[i]) {
      int p = atomicAdd(&rankS[bS_[i]], 1);
      stg2[p] = (u16)(pv_[i] & (BNODES - 1));   // local src id
      stg2b[p] = (u8)bS_[i];
    }
  }
  __syncthreads();
  int V = min(CHUNK, total - c0);
  for (int j = tid; j < V; j += ST) {
    int b = stgb[j];
    pairs[gbaseD[b] + (j - exclD[b])] = stgv[j];   // contiguous runs per bucket
  }
  int V2 = min(CHUNK, e - c0);                     // negative -> loop skipped
  for (int j = tid; j < V2; j += ST) {
    int b = stg2b[j];
    pairs2[gbaseS[b] + (j - exclS[b])] = stg2[j];
  }
}

// ---------- pass 3a: per-dst-bucket CSR finalize (rp, col, nin) ----------
__global__ __launch_bounds__(1024) void k_build(
    const u32* __restrict__ pairs, const int* __restrict__ bbase,
    int* __restrict__ rp, int* __restrict__ col,
    float* __restrict__ nin, int n, int nbuck, int total) {
  __shared__ int cnt[BNODES];
  __shared__ int off_[BNODES];
  __shared__ int cur[BNODES];
  int tid = threadIdx.x;            // 0..1023
  int b = blockIdx.x;
  int base = bbase[b], end = bbase[b + 1];
  int node0 = b << SHIFT;
  cnt[tid] = 0;
  __syncthreads();
  for (int t = base + tid; t < end; t += 1024)
    atomicAdd(&cnt[(int)(pairs[t] >> 22)], 1);
  __syncthreads();
  int c = cnt[tid];
  off_[tid] = c;
  __syncthreads();
  for (int off = 1; off < BNODES; off <<= 1) {
    int add = (tid >= off) ? off_[tid - off] : 0;
    __syncthreads();
    off_[tid] += add;
    __syncthreads();
  }
  int ex = off_[tid] - c;
  int node = node0 + tid;
  if (node < n) {
    rp[node] = base + ex;
    nin[node] = rsqrtf((float)c);              // in-degree incl self-loop
  }
  if (b == nbuck - 1 && tid == 0) rp[n] = total;
  cur[tid] = ex;
  __syncthreads();
  for (int t = base + tid; t < end; t += 1024) {
    u32 pr = pairs[t];
    int p = atomicAdd(&cur[(int)(pr >> 22)], 1);
    col[base + p] = (int)(pr & 0x3FFFFFu);
  }
}

// ---------- pass 3b: per-src-bucket out-degree -> nout ----------
__global__ __launch_bounds__(1024) void k_build2(
    const u16* __restrict__ pairs2, const int* __restrict__ bbaseS,
    float* __restrict__ nout, int n, int nbuck) {
  __shared__ int cnt[BNODES];
  int tid = threadIdx.x;
  int b = blockIdx.x;
  int base = bbaseS[b], end = bbaseS[b + 1];
  cnt[tid] = 0;
  __syncthreads();
  for (int t = base + tid; t < end; t += 1024)
    atomicAdd(&cnt[(int)pairs2[t]], 1);
  __syncthreads();
  int node = (b << SHIFT) + tid;
  if (node < n) nout[node] = rsqrtf((float)(cnt[tid] + 1));   // +1 self-loop
}

// ---------- pre-scale x by norm_out -> bf16; also zero the sentinel row n ----------
__global__ __launch_bounds__(256) void k_prescale(
    const float* __restrict__ x, const float* __restrict__ nout,
    u32* __restrict__ xs, int n) {
  int tot = (n + 1) * 64;   // float2 elements, incl zero row
  const float2* xv = (const float2*)x;
  for (int idx = blockIdx.x * blockDim.x + threadIdx.x; idx < tot;
       idx += gridDim.x * blockDim.x) {
    int row = idx >> 6;
    if (row >= n) { xs[idx] = 0; }
    else {
      float w = nout[row];
      float2 v = xv[idx];
      xs[idx] = (u32)f2bf(v.x * w) | ((u32)f2bf(v.y * w) << 16);
    }
  }
}

// ---------- W -> fragment-ordered split-bf16 (hi/lo planes); both W1 and W2 ----------
__global__ void k_prepw(const float* __restrict__ W1, u32* __restrict__ wf1hi,
                        u32* __restrict__ wf1lo,
                        const float* __restrict__ W2, u32* __restrict__ wf2hi,
                        u32* __restrict__ wf2lo) {
  int gi = blockIdx.x * 256 + threadIdx.x;   // 2 x 8192
  int i = gi & 8191;
  const float* W = (gi < 8192) ? W1 : W2;
  u32* wfhi = (gi < 8192) ? wf1hi : wf2hi;
  u32* wflo = (gi < 8192) ? wf1lo : wf2lo;
  int m = i & 3, l = (i >> 2) & 63, f = i >> 8;
  int kt = f & 3, nt = f >> 2;
  int k0 = kt * 32 + ((l >> 4) << 3) + 2 * m;
  int c = nt * 16 + (l & 15);
  float w0 = W[k0 * FD + c], w1 = W[(k0 + 1) * FD + c];
  u16 h0 = f2bf(w0), h1 = f2bf(w1);
  u16 l0 = f2bf(w0 - bf2f(h0)), l1 = f2bf(w1 - bf2f(h1));
  wfhi[i] = (u32)h0 | ((u32)h1 << 16);
  wflo[i] = (u32)l0 | ((u32)l1 << 16);
}

// ---------- aggregation: 4 rows per wave, one per 16-lane group ----------
// 8 independent full-row gathers in flight per trip; sentinel row n pads.
__global__ __launch_bounds__(256) void k_agg(
    const u32* __restrict__ hs, const int* __restrict__ rp,
    const int* __restrict__ col, const float* __restrict__ nin,
    u32* __restrict__ ahi, int n) {
  int wv = (blockIdx.x * 256 + threadIdx.x) >> 6;   // global wave id
  int lane = threadIdx.x & 63;
  int g = lane >> 4, ch = lane & 15;
  int r = wv * 4 + g;
  bool valid = (r < n);
  int e0 = 0, e1 = 0;
  if (valid) { e0 = rp[r]; e1 = rp[r + 1]; }   // e1 > e0 (self-loop)
  int m = e1 - e0;
  m = max(m, __shfl_xor(m, 16, 64));
  m = max(m, __shfl_xor(m, 32, 64));
  int trips = (m + 7) >> 3;
  float acc[8] = {0.f, 0.f, 0.f, 0.f, 0.f, 0.f, 0.f, 0.f};
  const u32x4* hv = (const u32x4*)hs;   // 16 chunks per row
  int em1 = (e1 > 0) ? (e1 - 1) : 0;
  for (int it = 0; it < trips; ++it) {
    int tb = e0 + it * 8;
    u32x4 buf[8];
    #pragma unroll
    for (int u = 0; u < 8; ++u) {
      int idx = tb + u;
      int s = col[min(idx, em1)];          // group-uniform broadcast load
      s = (idx < e1) ? s : n;              // sentinel zero row for pads
      buf[u] = hv[(size_t)s * 16 + ch];
    }
    #pragma unroll
    for (int u = 0; u < 8; ++u)
      #pragma unroll
      for (int j = 0; j < 4; ++j) {
        u32 x = buf[u][j];
        acc[2 * j]     += __uint_as_float(x << 16);
        acc[2 * j + 1] += __uint_as_float(x & 0xFFFF0000u);
      }
  }
  if (!valid) return;
  float wi = nin[r];
  u32 hi[4];
  #pragma unroll
  for (int j = 0; j < 4; ++j) {
    float v0 = acc[2 * j] * wi, v1 = acc[2 * j + 1] * wi;
    hi[j] = (u32)f2bf(v0) | ((u32)f2bf(v1) << 16);
  }
  int sch = ch ^ (r & 7);                 // 16B-chunk XOR swizzle
  u32x4 hq = {hi[0], hi[1], hi[2], hi[3]};
  *(u32x4*)(ahi + (size_t)r * 64 + sch * 4) = hq;
}

// ---------- MFMA GEMM: out[64xFD tile] = Ahi @ (Whi+Wlo) + bias ----------
__global__ __launch_bounds__(256) void k_gemm(
    const u32* __restrict__ ahi,
    const u32* __restrict__ wfhi, const u32* __restrict__ wflo,
    const float* __restrict__ bias, const float* __restrict__ nout,
    float* __restrict__ fout, u16* __restrict__ hsout, int n, int mode) {
  __shared__ u32 Ah[4096];   // 64 rows x 256B (swizzled), 16 KB
  int tid = threadIdx.x;
  int lane = tid & 63;
  int mt = tid >> 6;
  int r0 = blockIdx.x * 64;

  const u32x4* gh = (const u32x4*)(ahi + (size_t)r0 * 64);
  u32x4* sh_ = (u32x4*)Ah;
  #pragma unroll
  for (int t = 0; t < 4; ++t) sh_[t * 256 + tid] = gh[t * 256 + tid];
  __syncthreads();

  short8 afh[4];
  int arow = mt * 16 + (lane & 15);
  #pragma unroll
  for (int kt = 0; kt < 4; ++kt) {
    int boff = arow * 256 + ((kt * 64 + (lane >> 4) * 16) ^ ((arow & 7) << 4));
    afh[kt] = *(const short8*)((const char*)Ah + boff);
  }

  for (int nt = 0; nt < 8; ++nt) {
    f32x4 acc = {0.f, 0.f, 0.f, 0.f};
    #pragma unroll
    for (int kt = 0; kt < 4; ++kt) {
      int f = nt * 4 + kt;
      short8 wh = *(const short8*)(wfhi + (size_t)(f * 64 + lane) * 4);
      short8 wl = *(const short8*)(wflo + (size_t)(f * 64 + lane) * 4);
      acc = __builtin_amdgcn_mfma_f32_16x16x32_bf16(afh[kt], wh, acc, 0, 0, 0);
      acc = __builtin_amdgcn_mfma_f32_16x16x32_bf16(afh[kt], wl, acc, 0, 0, 0);
    }
    int c = nt * 16 + (lane & 15);
    float bv = bias[c];
    int rbase = r0 + mt * 16 + (lane >> 4) * 4;   // C/D: col=lane&15, row=(lane>>4)*4+j
    if (mode == 0) {
      #pragma unroll
      for (int j = 0; j < 4; ++j) {
        int row = rbase + j;
        if (row < n) fout[(size_t)row * FD + c] = acc[j] + bv;
      }
    } else {
      #pragma unroll
      for (int j = 0; j < 4; ++j) {
        int row = rbase + j;
        if (row < n) hsout[(size_t)row * FD + c] = f2bf((acc[j] + bv) * nout[row]);
      }
    }
  }
}

// ---------------- launch ----------------
extern "C" void kernel_launch(void* const* d_in, const int* in_sizes, int n_in,
                              void* d_out, int out_size, void* d_ws, size_t ws_size,
                              hipStream_t stream) {
  const float* x  = (const float*)d_in[0];
  const int* src  = (const int*)d_in[1];
  const int* dst  = (const int*)d_in[2];
  const float* W1 = (const float*)d_in[3];
  const float* b1 = (const float*)d_in[4];
  const float* W2 = (const float*)d_in[5];
  const float* b2 = (const float*)d_in[6];
  float* out = (float*)d_out;

  int n = in_sizes[0] / FD;      // 100000
  int e = in_sizes[1];           // 1600000
  int total = e + n;
  int nbuck = (n + BNODES - 1) >> SHIFT;   // 98

  char* ws = (char*)d_ws;
  size_t off = 0;
  auto alloc = [&](size_t bytes) -> void* {
    void* p = ws + off;
    off += (bytes + 255) / 256 * 256;
    return p;
  };
  // shared region: pairs (build) -> xs (prescale/agg1) -> h1s (gemm1/agg2)
  // row n is the zero sentinel row (zeroed by prescale; gemm writes only rows<n)
  u32* shared_ = (u32*)alloc((size_t)(n + 16) * 64 * 4);   // 25.6 MB
  u32* pairs = shared_;
  u32* xs    = shared_;
  u16* h1s   = (u16*)shared_;
  u32* ahi   = (u32*)alloc((size_t)(n + 64) * 64 * 4);  // 25.6 MB
  u16* pairs2 = (u16*)alloc((size_t)e * 2 + 256);       // 3.2 MB (src-keyed)
  int* col   = (int*)alloc((size_t)total * 4 + 256);    // 6.8 MB (+tail slack)
  int* rp    = (int*)alloc((size_t)(n + 1) * 4);
  float* nin  = (float*)alloc((size_t)n * 4);
  float* nout = (float*)alloc((size_t)n * 4);
  int* bcntD  = (int*)alloc(NBK * 4);
  int* bcntS  = (int*)alloc(NBK * 4);
  int* bbaseD = (int*)alloc((NBK + 1) * 4);
  int* bbaseS = (int*)alloc((NBK + 1) * 4);
  int* bcurD  = (int*)alloc(NBK * 4);
  int* bcurS  = (int*)alloc(NBK * 4);
  u32* wf1hi  = (u32*)alloc(8192 * 4);
  u32* wf1lo  = (u32*)alloc(8192 * 4);
  u32* wf2hi  = (u32*)alloc(8192 * 4);
  u32* wf2lo  = (u32*)alloc(8192 * 4);

  hipMemsetAsync(bcntD, 0, (size_t)NBK * 4 * 2, stream);   // bcntD+bcntS contiguous

  k_hist<<<256, 512, 0, stream>>>(src, dst, bcntD, bcntS, e, n, nbuck);
  k_bscan<<<1, NBK, 0, stream>>>(bcntD, bcntS, bbaseD, bcurD, bbaseS, bcurS,
                                 nbuck, total, e);
  k_scatter<<<(total + CHUNK - 1) / CHUNK, ST, 0, stream>>>(
      src, dst, bcurD, bcurS, pairs, pairs2, e, n, nbuck);
  k_build<<<nbuck, 1024, 0, stream>>>(pairs, bbaseD, rp, col, nin, n, nbuck, total);
  k_build2<<<nbuck, 1024, 0, stream>>>(pairs2, bbaseS, nout, n, nbuck);
  k_prepw<<<64, 256, 0, stream>>>(W1, wf1hi, wf1lo, W2, wf2hi, wf2lo);
  k_prescale<<<2048, 256, 0, stream>>>(x, nout, xs, n);

  int agrid = (n + 15) / 16;     // 4 rows/wave, 4 waves/block
  int ggrid = (n + 63) / 64;
  // layer 1
  k_agg<<<agrid, 256, 0, stream>>>(xs, rp, col, nin, ahi, n);
  k_gemm<<<ggrid, 256, 0, stream>>>(ahi, wf1hi, wf1lo, b1, nout,
                                    nullptr, h1s, n, 1);
  // layer 2
  k_agg<<<agrid, 256, 0, stream>>>((const u32*)h1s, rp, col, nin, ahi, n);
  k_gemm<<<ggrid, 256, 0, stream>>>(ahi, wf2hi, wf2lo, b2, nout,
                                    out, nullptr, n, 0);
}

// Round 9
// 235.926 us; speedup vs baseline: 2.7118x; 1.0642x over previous
//
#include <hip/hip_runtime.h>

#define FD 128
#define SHIFT 10         // nodes per bucket = 1024
#define BNODES 1024
#define NBK 128          // padded bucket-array size (98 used)
#define CHUNK 4096       // edges per scatter block
#define ST 512           // scatter block threads

typedef unsigned int u32;
typedef unsigned short u16;
typedef unsigned char u8;
typedef __attribute__((ext_vector_type(8))) short short8;   // 8 bf16 (4 VGPR)
typedef __attribute__((ext_vector_type(4))) float f32x4;
typedef __attribute__((ext_vector_type(4))) u32 u32x4;

__device__ inline u16 f2bf(float f) {            // fp32 -> bf16 RNE
  u32 u = __float_as_uint(f);
  u += 0x7fffu + ((u >> 16) & 1u);
  return (u16)(u >> 16);
}
__device__ inline float bf2f(u16 h) { return __uint_as_float((u32)h << 16); }

// ---------- pass 0: bucket histograms (dst incl self-loops; src real edges) ----------
__global__ __launch_bounds__(512) void k_hist(const int* __restrict__ src,
                                              const int* __restrict__ dst,
                                              int* __restrict__ bcntD,
                                              int* __restrict__ bcntS,
                                              int e, int n, int nbuck) {
  __shared__ int shD[NBK];
  __shared__ int shS[NBK];
  int tid = threadIdx.x;
  if (tid < NBK) { shD[tid] = 0; shS[tid] = 0; }
  __syncthreads();
  int total = e + n;
  for (int t = blockIdx.x * blockDim.x + tid; t < total; t += gridDim.x * blockDim.x) {
    if (t < e) {
      atomicAdd(&shD[dst[t] >> SHIFT], 1);
      atomicAdd(&shS[src[t] >> SHIFT], 1);
    } else {
      atomicAdd(&shD[(t - e) >> SHIFT], 1);
    }
  }
  __syncthreads();
  if (tid < nbuck) {
    if (shD[tid]) atomicAdd(&bcntD[tid], shD[tid]);
    if (shS[tid]) atomicAdd(&bcntS[tid], shS[tid]);
  }
}

// ---------- pass 1: scan both bucket arrays ----------
__global__ __launch_bounds__(NBK) void k_bscan(
    const int* __restrict__ bcntD, const int* __restrict__ bcntS,
    int* __restrict__ bbaseD, int* __restrict__ bcurD,
    int* __restrict__ bbaseS, int* __restrict__ bcurS,
    int nbuck, int totalD, int totalS) {
  __shared__ int shD[NBK];
  __shared__ int shS[NBK];
  int tid = threadIdx.x;
  int vD = (tid < nbuck) ? bcntD[tid] : 0;
  int vS = (tid < nbuck) ? bcntS[tid] : 0;
  shD[tid] = vD; shS[tid] = vS;
  __syncthreads();
  for (int off = 1; off < NBK; off <<= 1) {
    int aD = (tid >= off) ? shD[tid - off] : 0;
    int aS = (tid >= off) ? shS[tid - off] : 0;
    __syncthreads();
    shD[tid] += aD; shS[tid] += aS;
    __syncthreads();
  }
  if (tid < nbuck) {
    int exD = shD[tid] - vD; bbaseD[tid] = exD; bcurD[tid] = exD;
    int exS = shS[tid] - vS; bbaseS[tid] = exS; bcurS[tid] = exS;
  }
  if (tid == 0) { bbaseD[nbuck] = totalD; bbaseS[nbuck] = totalS; }
}

// ---------- pass 2: dual locality-aware scatter (dst-keyed u32, src-keyed u16) ----------
// NO per-node device atomics. pack: local_dst(10b) << 22 | src(22b)
__global__ __launch_bounds__(ST) void k_scatter(
    const int* __restrict__ src, const int* __restrict__ dst,
    int* __restrict__ bcurD, int* __restrict__ bcurS,
    u32* __restrict__ pairs, u16* __restrict__ pairs2,
    int e, int n, int nbuck) {
  __shared__ int histD[NBK], exclD[NBK], gbaseD[NBK], rankD[NBK];
  __shared__ int histS[NBK], exclS[NBK], gbaseS[NBK], rankS[NBK];
  __shared__ u32 stgv[CHUNK];
  __shared__ u8  stgb[CHUNK];
  __shared__ u16 stg2[CHUNK];
  __shared__ u8  stg2b[CHUNK];
  int tid = threadIdx.x;
  int c0 = blockIdx.x * CHUNK;
  int total = e + n;
  if (tid < NBK) { histD[tid] = 0; histS[tid] = 0; }
  __syncthreads();
  u32 pv_[8]; int bD_[8], bS_[8]; bool v_[8], vs_[8];
  #pragma unroll
  for (int i = 0; i < 8; ++i) {
    int t = c0 + i * ST + tid;
    v_[i] = (t < total);
    vs_[i] = (t < e);
    pv_[i] = 0; bD_[i] = 0; bS_[i] = 0;
    if (v_[i]) {
      int s, d;
      if (vs_[i]) { s = src[t]; d = dst[t]; }
      else        { s = t - e;  d = s; }
      pv_[i] = ((u32)(d & (BNODES - 1)) << 22) | (u32)s;
      bD_[i] = d >> SHIFT;
      atomicAdd(&histD[bD_[i]], 1);
      if (vs_[i]) { bS_[i] = s >> SHIFT; atomicAdd(&histS[bS_[i]], 1); }
    }
  }
  __syncthreads();
  int hD = 0, hS = 0;
  if (tid < NBK) { hD = histD[tid]; hS = histS[tid]; }
  __syncthreads();
  for (int off = 1; off < NBK; off <<= 1) {
    int aD = 0, aS = 0;
    if (tid < NBK && tid >= off) { aD = histD[tid - off]; aS = histS[tid - off]; }
    __syncthreads();
    if (tid < NBK) { histD[tid] += aD; histS[tid] += aS; }
    __syncthreads();
  }
  if (tid < NBK) {
    int exD = histD[tid] - hD; exclD[tid] = exD; rankD[tid] = exD;
    int exS = histS[tid] - hS; exclS[tid] = exS; rankS[tid] = exS;
    gbaseD[tid] = (tid < nbuck && hD > 0) ? atomicAdd(&bcurD[tid], hD) : 0;
    gbaseS[tid] = (tid < nbuck && hS > 0) ? atomicAdd(&bcurS[tid], hS) : 0;
  }
  __syncthreads();
  #pragma unroll
  for (int i = 0; i < 8; ++i) {
    if (v_[i]) {
      int p = atomicAdd(&rankD[bD_[i]], 1);
      stgv[p] = pv_[i];
      stgb[p] = (u8)bD_[i];
    }
    if (vs_[i]) {
      int p = atomicAdd(&rankS[bS_[i]], 1);
      stg2[p] = (u16)(pv_[i] & (BNODES - 1));   // local src id
      stg2b[p] = (u8)bS_[i];
    }
  }
  __syncthreads();
  int V = min(CHUNK, total - c0);
  for (int j = tid; j < V; j += ST) {
    int b = stgb[j];
    pairs[gbaseD[b] + (j - exclD[b])] = stgv[j];   // contiguous runs per bucket
  }
  int V2 = min(CHUNK, e - c0);                     // negative -> loop skipped
  for (int j = tid; j < V2; j += ST) {
    int b = stg2b[j];
    pairs2[gbaseS[b] + (j - exclS[b])] = stg2[j];
  }
}

// ---------- pass 3: merged per-bucket finalize ----------
// blocks [0, nbuck): CSR (rp, col, nin) from dst-keyed pairs
// blocks [nbuck, 2*nbuck): out-degree -> nout from src-keyed pairs2
__global__ __launch_bounds__(1024) void k_build(
    const u32* __restrict__ pairs, const int* __restrict__ bbase,
    const u16* __restrict__ pairs2, const int* __restrict__ bbaseS,
    int* __restrict__ rp, int* __restrict__ col,
    float* __restrict__ nin, float* __restrict__ nout,
    int n, int nbuck, int total) {
  __shared__ int cnt[BNODES];
  __shared__ int off_[BNODES];
  __shared__ int cur[BNODES];
  int tid = threadIdx.x;            // 0..1023
  if (blockIdx.x >= (unsigned)nbuck) {
    // ---- build2: out-degree ----
    int b = blockIdx.x - nbuck;
    int base = bbaseS[b], end = bbaseS[b + 1];
    cnt[tid] = 0;
    __syncthreads();
    for (int t = base + tid; t < end; t += 1024)
      atomicAdd(&cnt[(int)pairs2[t]], 1);
    __syncthreads();
    int node = (b << SHIFT) + tid;
    if (node < n) nout[node] = rsqrtf((float)(cnt[tid] + 1));   // +1 self-loop
    return;
  }
  int b = blockIdx.x;
  int base = bbase[b], end = bbase[b + 1];
  int node0 = b << SHIFT;
  cnt[tid] = 0;
  __syncthreads();
  for (int t = base + tid; t < end; t += 1024)
    atomicAdd(&cnt[(int)(pairs[t] >> 22)], 1);
  __syncthreads();
  int c = cnt[tid];
  off_[tid] = c;
  __syncthreads();
  for (int off = 1; off < BNODES; off <<= 1) {
    int add = (tid >= off) ? off_[tid - off] : 0;
    __syncthreads();
    off_[tid] += add;
    __syncthreads();
  }
  int ex = off_[tid] - c;
  int node = node0 + tid;
  if (node < n) {
    rp[node] = base + ex;
    nin[node] = rsqrtf((float)c);              // in-degree incl self-loop
  }
  if (b == nbuck - 1 && tid == 0) rp[n] = total;
  cur[tid] = ex;
  __syncthreads();
  for (int t = base + tid; t < end; t += 1024) {
    u32 pr = pairs[t];
    int p = atomicAdd(&cur[(int)(pr >> 22)], 1);
    col[base + p] = (int)(pr & 0x3FFFFFu);
  }
}

// ---------- pre-scale x by norm_out -> bf16; also zero the sentinel row n ----------
__global__ __launch_bounds__(256) void k_prescale(
    const float* __restrict__ x, const float* __restrict__ nout,
    u32* __restrict__ xs, int n) {
  int tot = (n + 1) * 64;   // float2 elements, incl zero row
  const float2* xv = (const float2*)x;
  for (int idx = blockIdx.x * blockDim.x + threadIdx.x; idx < tot;
       idx += gridDim.x * blockDim.x) {
    int row = idx >> 6;
    if (row >= n) { xs[idx] = 0; }
    else {
      float w = nout[row];
      float2 v = xv[idx];
      xs[idx] = (u32)f2bf(v.x * w) | ((u32)f2bf(v.y * w) << 16);
    }
  }
}

// ---------- W -> fragment-ordered split-bf16 (hi/lo planes); both W1 and W2 ----------
__global__ void k_prepw(const float* __restrict__ W1, u32* __restrict__ wf1hi,
                        u32* __restrict__ wf1lo,
                        const float* __restrict__ W2, u32* __restrict__ wf2hi,
                        u32* __restrict__ wf2lo) {
  int gi = blockIdx.x * 256 + threadIdx.x;   // 2 x 8192
  int i = gi & 8191;
  const float* W = (gi < 8192) ? W1 : W2;
  u32* wfhi = (gi < 8192) ? wf1hi : wf2hi;
  u32* wflo = (gi < 8192) ? wf1lo : wf2lo;
  int m = i & 3, l = (i >> 2) & 63, f = i >> 8;
  int kt = f & 3, nt = f >> 2;
  int k0 = kt * 32 + ((l >> 4) << 3) + 2 * m;
  int c = nt * 16 + (l & 15);
  float w0 = W[k0 * FD + c], w1 = W[(k0 + 1) * FD + c];
  u16 h0 = f2bf(w0), h1 = f2bf(w1);
  u16 l0 = f2bf(w0 - bf2f(h0)), l1 = f2bf(w1 - bf2f(h1));
  wfhi[i] = (u32)h0 | ((u32)h1 << 16);
  wflo[i] = (u32)l0 | ((u32)l1 << 16);
}

// ---------- fused layer: 16-row tile; gather-aggregate -> LDS -> MFMA GEMM ----------
// 256 thr = 4 waves. Agg: wave wv owns rows r0+wv*4..+3, one row per 16-lane
// group, 8 full-row gathers in flight. GEMM: 16-row A tile in LDS (4 KB,
// chunk-XOR swizzled), wave wv computes nt = 2*wv, 2*wv+1.
// mode 0: fp32 out ; mode 1: bf16(nout*val) for the next layer's gather.
__global__ __launch_bounds__(256, 8) void k_layer(
    const u32* __restrict__ hs, const int* __restrict__ rp,
    const int* __restrict__ col, const float* __restrict__ nin,
    const u32* __restrict__ wfhi, const u32* __restrict__ wflo,
    const float* __restrict__ bias, const float* __restrict__ nout,
    float* __restrict__ fout, u16* __restrict__ hsout, int n, int mode) {
  __shared__ u32 As[1024];   // 16 rows x 256B (swizzled)
  int tid = threadIdx.x;
  int lane = tid & 63;
  int wv = tid >> 6;
  int g = lane >> 4, ch = lane & 15;
  int r0 = blockIdx.x * 16;
  int lr = wv * 4 + g;            // local row 0..15
  int r = r0 + lr;
  bool valid = (r < n);

  // ---- aggregation phase ----
  int e0 = 0, e1 = 0;
  if (valid) { e0 = rp[r]; e1 = rp[r + 1]; }   // e1 > e0 (self-loop)
  int m = e1 - e0;
  m = max(m, __shfl_xor(m, 16, 64));
  m = max(m, __shfl_xor(m, 32, 64));
  int trips = (m + 7) >> 3;
  float acc[8] = {0.f, 0.f, 0.f, 0.f, 0.f, 0.f, 0.f, 0.f};
  const u32x4* hv = (const u32x4*)hs;   // 16 chunks per row
  int em1 = (e1 > 0) ? (e1 - 1) : 0;
  for (int it = 0; it < trips; ++it) {
    int tb = e0 + it * 8;
    u32x4 buf[8];
    #pragma unroll
    for (int u = 0; u < 8; ++u) {
      int idx = tb + u;
      int s = col[min(idx, em1)];          // group-uniform broadcast load
      s = (idx < e1) ? s : n;              // sentinel zero row for pads
      buf[u] = hv[(size_t)s * 16 + ch];
    }
    #pragma unroll
    for (int u = 0; u < 8; ++u)
      #pragma unroll
      for (int j = 0; j < 4; ++j) {
        u32 x = buf[u][j];
        acc[2 * j]     += __uint_as_float(x << 16);
        acc[2 * j + 1] += __uint_as_float(x & 0xFFFF0000u);
      }
  }
  float wi = valid ? nin[r] : 0.f;
  u32 hi[4];
  #pragma unroll
  for (int j = 0; j < 4; ++j) {
    float v0 = acc[2 * j] * wi, v1 = acc[2 * j + 1] * wi;
    hi[j] = (u32)f2bf(v0) | ((u32)f2bf(v1) << 16);
  }
  int sch = ch ^ (lr & 7);                 // 16B-chunk XOR swizzle
  u32x4 hq = {hi[0], hi[1], hi[2], hi[3]};
  *(u32x4*)(As + lr * 64 + sch * 4) = hq;
  __syncthreads();

  // ---- GEMM phase ----
  short8 afh[4];
  int arow = lane & 15;
  #pragma unroll
  for (int kt = 0; kt < 4; ++kt) {
    int boff = arow * 256 + ((kt * 64 + (lane >> 4) * 16) ^ ((arow & 7) << 4));
    afh[kt] = *(const short8*)((const char*)As + boff);
  }
  #pragma unroll
  for (int q = 0; q < 2; ++q) {
    int nt = wv * 2 + q;
    f32x4 oacc = {0.f, 0.f, 0.f, 0.f};
    #pragma unroll
    for (int kt = 0; kt < 4; ++kt) {
      int f = nt * 4 + kt;
      short8 wh = *(const short8*)(wfhi + (size_t)(f * 64 + lane) * 4);
      short8 wl = *(const short8*)(wflo + (size_t)(f * 64 + lane) * 4);
      oacc = __builtin_amdgcn_mfma_f32_16x16x32_bf16(afh[kt], wh, oacc, 0, 0, 0);
      oacc = __builtin_amdgcn_mfma_f32_16x16x32_bf16(afh[kt], wl, oacc, 0, 0, 0);
    }
    int c = nt * 16 + (lane & 15);
    float bv = bias[c];
    int rbase = r0 + (lane >> 4) * 4;   // C/D: col=lane&15, row=(lane>>4)*4+j
    if (mode == 0) {
      #pragma unroll
      for (int j = 0; j < 4; ++j) {
        int row = rbase + j;
        if (row < n) fout[(size_t)row * FD + c] = oacc[j] + bv;
      }
    } else {
      #pragma unroll
      for (int j = 0; j < 4; ++j) {
        int row = rbase + j;
        if (row < n) hsout[(size_t)row * FD + c] = f2bf((oacc[j] + bv) * nout[row]);
      }
    }
  }
}

// ---------------- launch ----------------
extern "C" void kernel_launch(void* const* d_in, const int* in_sizes, int n_in,
                              void* d_out, int out_size, void* d_ws, size_t ws_size,
                              hipStream_t stream) {
  const float* x  = (const float*)d_in[0];
  const int* src  = (const int*)d_in[1];
  const int* dst  = (const int*)d_in[2];
  const float* W1 = (const float*)d_in[3];
  const float* b1 = (const float*)d_in[4];
  const float* W2 = (const float*)d_in[5];
  const float* b2 = (const float*)d_in[6];
  float* out = (float*)d_out;

  int n = in_sizes[0] / FD;      // 100000
  int e = in_sizes[1];           // 1600000
  int total = e + n;
  int nbuck = (n + BNODES - 1) >> SHIFT;   // 98

  char* ws = (char*)d_ws;
  size_t off = 0;
  auto alloc = [&](size_t bytes) -> void* {
    void* p = ws + off;
    off += (bytes + 255) / 256 * 256;
    return p;
  };
  // xs region also hosts pairs (dead before prescale writes xs)
  u32* xs    = (u32*)alloc((size_t)(n + 16) * 64 * 4);   // 25.6 MB
  u32* pairs = xs;
  u16* h1s   = (u16*)alloc((size_t)(n + 16) * FD * 2);   // 25.6 MB (own buffer!)
  u16* pairs2 = (u16*)alloc((size_t)e * 2 + 256);        // 3.2 MB (src-keyed)
  int* col   = (int*)alloc((size_t)total * 4 + 256);     // 6.8 MB (+tail slack)
  int* rp    = (int*)alloc((size_t)(n + 1) * 4);
  float* nin  = (float*)alloc((size_t)n * 4);
  float* nout = (float*)alloc((size_t)n * 4);
  int* bcntD  = (int*)alloc(NBK * 4);
  int* bcntS  = (int*)alloc(NBK * 4);
  int* bbaseD = (int*)alloc((NBK + 1) * 4);
  int* bbaseS = (int*)alloc((NBK + 1) * 4);
  int* bcurD  = (int*)alloc(NBK * 4);
  int* bcurS  = (int*)alloc(NBK * 4);
  u32* wf1hi  = (u32*)alloc(8192 * 4);
  u32* wf1lo  = (u32*)alloc(8192 * 4);
  u32* wf2hi  = (u32*)alloc(8192 * 4);
  u32* wf2lo  = (u32*)alloc(8192 * 4);

  hipMemsetAsync(bcntD, 0, (size_t)NBK * 4 * 2, stream);   // bcntD+bcntS contiguous
  hipMemsetAsync(h1s + (size_t)n * FD, 0, FD * 2, stream); // h1s sentinel row

  k_hist<<<256, 512, 0, stream>>>(src, dst, bcntD, bcntS, e, n, nbuck);
  k_bscan<<<1, NBK, 0, stream>>>(bcntD, bcntS, bbaseD, bcurD, bbaseS, bcurS,
                                 nbuck, total, e);
  k_scatter<<<(total + CHUNK - 1) / CHUNK, ST, 0, stream>>>(
      src, dst, bcurD, bcurS, pairs, pairs2, e, n, nbuck);
  k_build<<<2 * nbuck, 1024, 0, stream>>>(pairs, bbaseD, pairs2, bbaseS,
                                          rp, col, nin, nout, n, nbuck, total);
  k_prepw<<<64, 256, 0, stream>>>(W1, wf1hi, wf1lo, W2, wf2hi, wf2lo);
  k_prescale<<<2048, 256, 0, stream>>>(x, nout, xs, n);

  int lgrid = (n + 15) / 16;     // 6250 blocks, 16 rows each
  // layer 1: gathers xs, writes h1s (separate buffer -> no race)
  k_layer<<<lgrid, 256, 0, stream>>>(xs, rp, col, nin, wf1hi, wf1lo, b1, nout,
                                     nullptr, h1s, n, 1);
  // layer 2: gathers h1s, writes fp32 out
  k_layer<<<lgrid, 256, 0, stream>>>((const u32*)h1s, rp, col, nin, wf2hi, wf2lo,
                                     b2, nout, out, nullptr, n, 0);
}

// Round 10
// 228.532 us; speedup vs baseline: 2.7995x; 1.0324x over previous
//
#include <hip/hip_runtime.h>

#define FD 128
#define SHIFT 10         // nodes per bucket = 1024
#define BNODES 1024
#define NBK 128          // padded bucket-array size (98 used)
#define CHUNK 4096       // edges per scatter block
#define ST 512           // scatter block threads
#define NE 12            // edges in flight per row-group in k_layer

typedef unsigned int u32;
typedef unsigned short u16;
typedef unsigned char u8;
typedef __attribute__((ext_vector_type(8))) short short8;   // 8 bf16 (4 VGPR)
typedef __attribute__((ext_vector_type(4))) float f32x4;
typedef __attribute__((ext_vector_type(4))) u32 u32x4;

__device__ inline u16 f2bf(float f) {            // fp32 -> bf16 RNE
  u32 u = __float_as_uint(f);
  u += 0x7fffu + ((u >> 16) & 1u);
  return (u16)(u >> 16);
}
__device__ inline float bf2f(u16 h) { return __uint_as_float((u32)h << 16); }

// ---------- pass 0: bucket histograms (dst incl self-loops; src real edges) ----------
__global__ __launch_bounds__(512) void k_hist(const int* __restrict__ src,
                                              const int* __restrict__ dst,
                                              int* __restrict__ bcntD,
                                              int* __restrict__ bcntS,
                                              int e, int n, int nbuck) {
  __shared__ int shD[NBK];
  __shared__ int shS[NBK];
  int tid = threadIdx.x;
  if (tid < NBK) { shD[tid] = 0; shS[tid] = 0; }
  __syncthreads();
  int total = e + n;
  for (int t = blockIdx.x * blockDim.x + tid; t < total; t += gridDim.x * blockDim.x) {
    if (t < e) {
      atomicAdd(&shD[dst[t] >> SHIFT], 1);
      atomicAdd(&shS[src[t] >> SHIFT], 1);
    } else {
      atomicAdd(&shD[(t - e) >> SHIFT], 1);
    }
  }
  __syncthreads();
  if (tid < nbuck) {
    if (shD[tid]) atomicAdd(&bcntD[tid], shD[tid]);
    if (shS[tid]) atomicAdd(&bcntS[tid], shS[tid]);
  }
}

// ---------- pass 1: scan both bucket arrays ----------
__global__ __launch_bounds__(NBK) void k_bscan(
    const int* __restrict__ bcntD, const int* __restrict__ bcntS,
    int* __restrict__ bbaseD, int* __restrict__ bcurD,
    int* __restrict__ bbaseS, int* __restrict__ bcurS,
    int nbuck, int totalD, int totalS) {
  __shared__ int shD[NBK];
  __shared__ int shS[NBK];
  int tid = threadIdx.x;
  int vD = (tid < nbuck) ? bcntD[tid] : 0;
  int vS = (tid < nbuck) ? bcntS[tid] : 0;
  shD[tid] = vD; shS[tid] = vS;
  __syncthreads();
  for (int off = 1; off < NBK; off <<= 1) {
    int aD = (tid >= off) ? shD[tid - off] : 0;
    int aS = (tid >= off) ? shS[tid - off] : 0;
    __syncthreads();
    shD[tid] += aD; shS[tid] += aS;
    __syncthreads();
  }
  if (tid < nbuck) {
    int exD = shD[tid] - vD; bbaseD[tid] = exD; bcurD[tid] = exD;
    int exS = shS[tid] - vS; bbaseS[tid] = exS; bcurS[tid] = exS;
  }
  if (tid == 0) { bbaseD[nbuck] = totalD; bbaseS[nbuck] = totalS; }
}

// ---------- pass 2: dual locality-aware scatter (dst-keyed u32, src-keyed u16) ----------
// NO per-node device atomics. pack: local_dst(10b) << 22 | src(22b)
__global__ __launch_bounds__(ST) void k_scatter(
    const int* __restrict__ src, const int* __restrict__ dst,
    int* __restrict__ bcurD, int* __restrict__ bcurS,
    u32* __restrict__ pairs, u16* __restrict__ pairs2,
    int e, int n, int nbuck) {
  __shared__ int histD[NBK], exclD[NBK], gbaseD[NBK], rankD[NBK];
  __shared__ int histS[NBK], exclS[NBK], gbaseS[NBK], rankS[NBK];
  __shared__ u32 stgv[CHUNK];
  __shared__ u8  stgb[CHUNK];
  __shared__ u16 stg2[CHUNK];
  __shared__ u8  stg2b[CHUNK];
  int tid = threadIdx.x;
  int c0 = blockIdx.x * CHUNK;
  int total = e + n;
  if (tid < NBK) { histD[tid] = 0; histS[tid] = 0; }
  __syncthreads();
  u32 pv_[8]; int bD_[8], bS_[8]; bool v_[8], vs_[8];
  #pragma unroll
  for (int i = 0; i < 8; ++i) {
    int t = c0 + i * ST + tid;
    v_[i] = (t < total);
    vs_[i] = (t < e);
    pv_[i] = 0; bD_[i] = 0; bS_[i] = 0;
    if (v_[i]) {
      int s, d;
      if (vs_[i]) { s = src[t]; d = dst[t]; }
      else        { s = t - e;  d = s; }
      pv_[i] = ((u32)(d & (BNODES - 1)) << 22) | (u32)s;
      bD_[i] = d >> SHIFT;
      atomicAdd(&histD[bD_[i]], 1);
      if (vs_[i]) { bS_[i] = s >> SHIFT; atomicAdd(&histS[bS_[i]], 1); }
    }
  }
  __syncthreads();
  int hD = 0, hS = 0;
  if (tid < NBK) { hD = histD[tid]; hS = histS[tid]; }
  __syncthreads();
  for (int off = 1; off < NBK; off <<= 1) {
    int aD = 0, aS = 0;
    if (tid < NBK && tid >= off) { aD = histD[tid - off]; aS = histS[tid - off]; }
    __syncthreads();
    if (tid < NBK) { histD[tid] += aD; histS[tid] += aS; }
    __syncthreads();
  }
  if (tid < NBK) {
    int exD = histD[tid] - hD; exclD[tid] = exD; rankD[tid] = exD;
    int exS = histS[tid] - hS; exclS[tid] = exS; rankS[tid] = exS;
    gbaseD[tid] = (tid < nbuck && hD > 0) ? atomicAdd(&bcurD[tid], hD) : 0;
    gbaseS[tid] = (tid < nbuck && hS > 0) ? atomicAdd(&bcurS[tid], hS) : 0;
  }
  __syncthreads();
  #pragma unroll
  for (int i = 0; i < 8; ++i) {
    if (v_[i]) {
      int p = atomicAdd(&rankD[bD_[i]], 1);
      stgv[p] = pv_[i];
      stgb[p] = (u8)bD_[i];
    }
    if (vs_[i]) {
      int p = atomicAdd(&rankS[bS_[i]], 1);
      stg2[p] = (u16)(pv_[i] & (BNODES - 1));   // local src id
      stg2b[p] = (u8)bS_[i];
    }
  }
  __syncthreads();
  int V = min(CHUNK, total - c0);
  for (int j = tid; j < V; j += ST) {
    int b = stgb[j];
    pairs[gbaseD[b] + (j - exclD[b])] = stgv[j];   // contiguous runs per bucket
  }
  int V2 = min(CHUNK, e - c0);                     // negative -> loop skipped
  for (int j = tid; j < V2; j += ST) {
    int b = stg2b[j];
    pairs2[gbaseS[b] + (j - exclS[b])] = stg2[j];
  }
}

// ---------- pass 3: merged per-bucket finalize ----------
// blocks [0, nbuck): CSR (rp, col, nin) from dst-keyed pairs
// blocks [nbuck, 2*nbuck): out-degree -> nout from src-keyed pairs2
__global__ __launch_bounds__(1024) void k_build(
    const u32* __restrict__ pairs, const int* __restrict__ bbase,
    const u16* __restrict__ pairs2, const int* __restrict__ bbaseS,
    int* __restrict__ rp, int* __restrict__ col,
    float* __restrict__ nin, float* __restrict__ nout,
    int n, int nbuck, int total) {
  __shared__ int cnt[BNODES];
  __shared__ int off_[BNODES];
  __shared__ int cur[BNODES];
  int tid = threadIdx.x;            // 0..1023
  if (blockIdx.x >= (unsigned)nbuck) {
    // ---- build2: out-degree ----
    int b = blockIdx.x - nbuck;
    int base = bbaseS[b], end = bbaseS[b + 1];
    cnt[tid] = 0;
    __syncthreads();
    for (int t = base + tid; t < end; t += 1024)
      atomicAdd(&cnt[(int)pairs2[t]], 1);
    __syncthreads();
    int node = (b << SHIFT) + tid;
    if (node < n) nout[node] = rsqrtf((float)(cnt[tid] + 1));   // +1 self-loop
    return;
  }
  int b = blockIdx.x;
  int base = bbase[b], end = bbase[b + 1];
  int node0 = b << SHIFT;
  cnt[tid] = 0;
  __syncthreads();
  for (int t = base + tid; t < end; t += 1024)
    atomicAdd(&cnt[(int)(pairs[t] >> 22)], 1);
  __syncthreads();
  int c = cnt[tid];
  off_[tid] = c;
  __syncthreads();
  for (int off = 1; off < BNODES; off <<= 1) {
    int add = (tid >= off) ? off_[tid - off] : 0;
    __syncthreads();
    off_[tid] += add;
    __syncthreads();
  }
  int ex = off_[tid] - c;
  int node = node0 + tid;
  if (node < n) {
    rp[node] = base + ex;
    nin[node] = rsqrtf((float)c);              // in-degree incl self-loop
  }
  if (b == nbuck - 1 && tid == 0) rp[n] = total;
  cur[tid] = ex;
  __syncthreads();
  for (int t = base + tid; t < end; t += 1024) {
    u32 pr = pairs[t];
    int p = atomicAdd(&cur[(int)(pr >> 22)], 1);
    col[base + p] = (int)(pr & 0x3FFFFFu);
  }
}

// ---------- pre-scale x by norm_out -> bf16; also zero the sentinel row n ----------
__global__ __launch_bounds__(256) void k_prescale(
    const float* __restrict__ x, const float* __restrict__ nout,
    u32* __restrict__ xs, int n) {
  int tot = (n + 1) * 64;   // float2 elements, incl zero row
  const float2* xv = (const float2*)x;
  for (int idx = blockIdx.x * blockDim.x + threadIdx.x; idx < tot;
       idx += gridDim.x * blockDim.x) {
    int row = idx >> 6;
    if (row >= n) { xs[idx] = 0; }
    else {
      float w = nout[row];
      float2 v = xv[idx];
      xs[idx] = (u32)f2bf(v.x * w) | ((u32)f2bf(v.y * w) << 16);
    }
  }
}

// ---------- W -> fragment-ordered split-bf16 (hi/lo planes); both W1 and W2 ----------
__global__ void k_prepw(const float* __restrict__ W1, u32* __restrict__ wf1hi,
                        u32* __restrict__ wf1lo,
                        const float* __restrict__ W2, u32* __restrict__ wf2hi,
                        u32* __restrict__ wf2lo) {
  int gi = blockIdx.x * 256 + threadIdx.x;   // 2 x 8192
  int i = gi & 8191;
  const float* W = (gi < 8192) ? W1 : W2;
  u32* wfhi = (gi < 8192) ? wf1hi : wf2hi;
  u32* wflo = (gi < 8192) ? wf1lo : wf2lo;
  int m = i & 3, l = (i >> 2) & 63, f = i >> 8;
  int kt = f & 3, nt = f >> 2;
  int k0 = kt * 32 + ((l >> 4) << 3) + 2 * m;
  int c = nt * 16 + (l & 15);
  float w0 = W[k0 * FD + c], w1 = W[(k0 + 1) * FD + c];
  u16 h0 = f2bf(w0), h1 = f2bf(w1);
  u16 l0 = f2bf(w0 - bf2f(h0)), l1 = f2bf(w1 - bf2f(h1));
  wfhi[i] = (u32)h0 | ((u32)h1 << 16);
  wflo[i] = (u32)l0 | ((u32)l1 << 16);
}

// ---------- fused layer: 16-row tile; deep-pipelined gather -> LDS -> MFMA ----------
// 256 thr = 4 waves. Agg: wave wv owns rows r0+wv*4..+3, one row per 16-lane
// group, NE=12 full-row gathers forced in flight (sched_barrier fences the
// issue loop from the unpack loop; col indices for the next trip prefetched).
// GEMM: 16-row A tile in LDS (4 KB, chunk-XOR swizzled), wave wv does nt=2wv,2wv+1.
// mode 0: fp32 out ; mode 1: bf16(nout*val) staged in LDS, coalesced 16B stores.
__global__ __launch_bounds__(256) void k_layer(
    const u32* __restrict__ hs, const int* __restrict__ rp,
    const int* __restrict__ col, const float* __restrict__ nin,
    const u32* __restrict__ wfhi, const u32* __restrict__ wflo,
    const float* __restrict__ bias, const float* __restrict__ nout,
    float* __restrict__ fout, u32* __restrict__ hsout, int n, int mode) {
  __shared__ u32 As[1024];   // 16 rows x 256B (swizzled); reused for mode-1 staging
  int tid = threadIdx.x;
  int lane = tid & 63;
  int wv = tid >> 6;
  int g = lane >> 4, ch = lane & 15;
  int r0 = blockIdx.x * 16;
  int lr = wv * 4 + g;            // local row 0..15
  int r = r0 + lr;
  bool valid = (r < n);

  // ---- aggregation phase ----
  int e0 = 0, e1 = 0;
  if (valid) { e0 = rp[r]; e1 = rp[r + 1]; }   // e1 > e0 (self-loop)
  int m = e1 - e0;
  m = max(m, __shfl_xor(m, 16, 64));
  m = max(m, __shfl_xor(m, 32, 64));
  int trips = (m + NE - 1) / NE;
  float acc[8] = {0.f, 0.f, 0.f, 0.f, 0.f, 0.f, 0.f, 0.f};
  const u32x4* hv = (const u32x4*)hs;   // 16 chunks per row
  int em1 = (e1 > 0) ? (e1 - 1) : 0;

  int cs[NE], csn[NE];
  #pragma unroll
  for (int u = 0; u < NE; ++u) cs[u] = col[min(e0 + u, em1)];
  for (int it = 0; it < trips; ++it) {
    int tb = e0 + it * NE;
    u32x4 buf[NE];
    #pragma unroll
    for (int u = 0; u < NE; ++u) {
      int s = (tb + u < e1) ? cs[u] : n;   // sentinel zero row for pads
      buf[u] = hv[(size_t)s * 16 + ch];
    }
    #pragma unroll
    for (int u = 0; u < NE; ++u) csn[u] = col[min(tb + NE + u, em1)];
    __builtin_amdgcn_sched_barrier(0);     // all NE gathers + next cols issued first
    #pragma unroll
    for (int u = 0; u < NE; ++u)
      #pragma unroll
      for (int j = 0; j < 4; ++j) {
        u32 x = buf[u][j];
        acc[2 * j]     += __uint_as_float(x << 16);
        acc[2 * j + 1] += __uint_as_float(x & 0xFFFF0000u);
      }
    #pragma unroll
    for (int u = 0; u < NE; ++u) cs[u] = csn[u];
  }
  float wi = valid ? nin[r] : 0.f;
  u32 hi[4];
  #pragma unroll
  for (int j = 0; j < 4; ++j) {
    float v0 = acc[2 * j] * wi, v1 = acc[2 * j + 1] * wi;
    hi[j] = (u32)f2bf(v0) | ((u32)f2bf(v1) << 16);
  }
  int sch = ch ^ (lr & 7);                 // 16B-chunk XOR swizzle
  u32x4 hq = {hi[0], hi[1], hi[2], hi[3]};
  *(u32x4*)(As + lr * 64 + sch * 4) = hq;
  __syncthreads();

  // ---- GEMM phase ----
  short8 afh[4];
  int arow = lane & 15;
  #pragma unroll
  for (int kt = 0; kt < 4; ++kt) {
    int boff = arow * 256 + ((kt * 64 + (lane >> 4) * 16) ^ ((arow & 7) << 4));
    afh[kt] = *(const short8*)((const char*)As + boff);
  }
  __syncthreads();   // all waves hold their A-frags; As is now dead (mode-1 reuse)

  #pragma unroll
  for (int q = 0; q < 2; ++q) {
    int nt = wv * 2 + q;
    f32x4 oacc = {0.f, 0.f, 0.f, 0.f};
    #pragma unroll
    for (int kt = 0; kt < 4; ++kt) {
      int f = nt * 4 + kt;
      short8 wh = *(const short8*)(wfhi + (size_t)(f * 64 + lane) * 4);
      short8 wl = *(const short8*)(wflo + (size_t)(f * 64 + lane) * 4);
      oacc = __builtin_amdgcn_mfma_f32_16x16x32_bf16(afh[kt], wh, oacc, 0, 0, 0);
      oacc = __builtin_amdgcn_mfma_f32_16x16x32_bf16(afh[kt], wl, oacc, 0, 0, 0);
    }
    int c = nt * 16 + (lane & 15);
    float bv = bias[c];
    int rbase = r0 + (lane >> 4) * 4;   // C/D: col=lane&15, row=(lane>>4)*4+j
    if (mode == 0) {
      #pragma unroll
      for (int j = 0; j < 4; ++j) {
        int row = rbase + j;
        if (row < n) fout[(size_t)row * FD + c] = oacc[j] + bv;
      }
    } else {
      // stage bf16 into As (natural layout) for coalesced stores
      #pragma unroll
      for (int j = 0; j < 4; ++j) {
        int row = rbase + j;
        float w = (row < n) ? nout[row] : 0.f;
        ((u16*)As)[(row - r0) * 128 + c] = f2bf((oacc[j] + bv) * w);
      }
    }
  }
  if (mode == 1) {
    __syncthreads();
    int row = tid >> 4, chk = tid & 15;
    if (r0 + row < n)
      *(u32x4*)(hsout + (size_t)(r0 + row) * 64 + chk * 4) =
          *(const u32x4*)(As + row * 64 + chk * 4);
  }
}

// ---------------- launch ----------------
extern "C" void kernel_launch(void* const* d_in, const int* in_sizes, int n_in,
                              void* d_out, int out_size, void* d_ws, size_t ws_size,
                              hipStream_t stream) {
  const float* x  = (const float*)d_in[0];
  const int* src  = (const int*)d_in[1];
  const int* dst  = (const int*)d_in[2];
  const float* W1 = (const float*)d_in[3];
  const float* b1 = (const float*)d_in[4];
  const float* W2 = (const float*)d_in[5];
  const float* b2 = (const float*)d_in[6];
  float* out = (float*)d_out;

  int n = in_sizes[0] / FD;      // 100000
  int e = in_sizes[1];           // 1600000
  int total = e + n;
  int nbuck = (n + BNODES - 1) >> SHIFT;   // 98

  char* ws = (char*)d_ws;
  size_t off = 0;
  auto alloc = [&](size_t bytes) -> void* {
    void* p = ws + off;
    off += (bytes + 255) / 256 * 256;
    return p;
  };
  // xs region also hosts pairs (dead before prescale writes xs)
  u32* xs    = (u32*)alloc((size_t)(n + 16) * 64 * 4);   // 25.6 MB
  u32* pairs = xs;
  u32* h1s   = (u32*)alloc((size_t)(n + 16) * 64 * 4);   // 25.6 MB (own buffer)
  u16* pairs2 = (u16*)alloc((size_t)e * 2 + 256);        // 3.2 MB (src-keyed)
  int* col   = (int*)alloc((size_t)total * 4 + 256);     // 6.8 MB (+tail slack)
  int* rp    = (int*)alloc((size_t)(n + 1) * 4);
  float* nin  = (float*)alloc((size_t)n * 4);
  float* nout = (float*)alloc((size_t)n * 4);
  int* bcntD  = (int*)alloc(NBK * 4);
  int* bcntS  = (int*)alloc(NBK * 4);
  int* bbaseD = (int*)alloc((NBK + 1) * 4);
  int* bbaseS = (int*)alloc((NBK + 1) * 4);
  int* bcurD  = (int*)alloc(NBK * 4);
  int* bcurS  = (int*)alloc(NBK * 4);
  u32* wf1hi  = (u32*)alloc(8192 * 4);
  u32* wf1lo  = (u32*)alloc(8192 * 4);
  u32* wf2hi  = (u32*)alloc(8192 * 4);
  u32* wf2lo  = (u32*)alloc(8192 * 4);

  hipMemsetAsync(bcntD, 0, (size_t)NBK * 4 * 2, stream);   // bcntD+bcntS contiguous
  hipMemsetAsync(h1s + (size_t)n * 64, 0, FD * 2, stream); // h1s sentinel row

  k_hist<<<256, 512, 0, stream>>>(src, dst, bcntD, bcntS, e, n, nbuck);
  k_bscan<<<1, NBK, 0, stream>>>(bcntD, bcntS, bbaseD, bcurD, bbaseS, bcurS,
                                 nbuck, total, e);
  k_scatter<<<(total + CHUNK - 1) / CHUNK, ST, 0, stream>>>(
      src, dst, bcurD, bcurS, pairs, pairs2, e, n, nbuck);
  k_build<<<2 * nbuck, 1024, 0, stream>>>(pairs, bbaseD, pairs2, bbaseS,
                                          rp, col, nin, nout, n, nbuck, total);
  k_prepw<<<64, 256, 0, stream>>>(W1, wf1hi, wf1lo, W2, wf2hi, wf2lo);
  k_prescale<<<2048, 256, 0, stream>>>(x, nout, xs, n);

  int lgrid = (n + 15) / 16;     // 6250 blocks, 16 rows each
  // layer 1: gathers xs, writes h1s (separate buffer -> no race)
  k_layer<<<lgrid, 256, 0, stream>>>(xs, rp, col, nin, wf1hi, wf1lo, b1, nout,
                                     nullptr, h1s, n, 1);
  // layer 2: gathers h1s, writes fp32 out
  k_layer<<<lgrid, 256, 0, stream>>>(h1s, rp, col, nin, wf2hi, wf2lo,
                                     b2, nout, out, nullptr, n, 0);
}